// Round 8
// baseline (1298.866 us; speedup 1.0000x reference)
//
#include <hip/hip_runtime.h>
#include <math.h>

#define SEQ 197
#define EMB 768
#define NH  12
#define HD  64
#define NE  28

typedef __attribute__((ext_vector_type(8))) __bf16 bf16x8;
typedef __attribute__((ext_vector_type(4))) float  f32x4;
typedef __attribute__((ext_vector_type(8))) float  f32x8;

__device__ __forceinline__ unsigned short f2bf(float f) {
    unsigned u = __float_as_uint(f);
    u += 0x7fffu + ((u >> 16) & 1u);
    return (unsigned short)(u >> 16);
}
__device__ __forceinline__ float bfl(unsigned u) { return __uint_as_float(u << 16); }
__device__ __forceinline__ float bfh(unsigned u) { return __uint_as_float(u & 0xffff0000u); }
__device__ __forceinline__ f32x8 unpk8v(uint4 v) {
    f32x8 r;
    r[0] = bfl(v.x); r[1] = bfh(v.x); r[2] = bfl(v.y); r[3] = bfh(v.y);
    r[4] = bfl(v.z); r[5] = bfh(v.z); r[6] = bfl(v.w); r[7] = bfh(v.w);
    return r;
}

__device__ __forceinline__ void gl_lds16(const ushort* g, ushort* l) {
    __builtin_amdgcn_global_load_lds(
        (const __attribute__((address_space(1))) unsigned int*)g,
        (__attribute__((address_space(3))) unsigned int*)l, 16, 0, 0);
}

// ---------------------------------------------------------------------------
// fp32 -> bf16 converters
// ---------------------------------------------------------------------------
__global__ void cvt_k(const float* __restrict__ src, ushort* __restrict__ dst, int n4) {
    int i = blockIdx.x * 256 + threadIdx.x;
    if (i < n4) {
        float4 v = ((const float4*)src)[i];
        ushort4 o = { f2bf(v.x), f2bf(v.y), f2bf(v.z), f2bf(v.w) };
        ((ushort4*)dst)[i] = o;
    }
}

__global__ void cvt_w4(const float* __restrict__ wq, const float* __restrict__ wk,
                       const float* __restrict__ wv, const float* __restrict__ wo,
                       ushort* __restrict__ wqkv, ushort* __restrict__ wob) {
    int i = blockIdx.x * 256 + threadIdx.x;          // 4 * 147456 total
    if (i >= 4 * 147456) return;
    int seg = i / 147456, r = i - seg * 147456;
    const float* s = (seg == 0) ? wq : (seg == 1) ? wk : (seg == 2) ? wv : wo;
    float4 v = ((const float4*)s)[r];
    ushort4 o = { f2bf(v.x), f2bf(v.y), f2bf(v.z), f2bf(v.w) };
    if (seg < 3) ((ushort4*)wqkv)[(size_t)seg * 147456 + r] = o;
    else         ((ushort4*)wob)[r] = o;
}

// ---------------------------------------------------------------------------
// bf16 MFMA GEMM (m97 pattern).
// MODE 0: A=x_bf16, W=packed Wqkv; q -> fp32, k,v -> bf16, all (b,h,s,d).
// MODE 1: A=attn_out bf16, W=Wo; out -> fp32 row-major (M,768).
// ---------------------------------------------------------------------------
template<int MODE>
__global__ __launch_bounds__(256, 2) void mfma_gemm(
    const ushort* __restrict__ A, const ushort* __restrict__ W,
    const float* __restrict__ b0, const float* __restrict__ b1, const float* __restrict__ b2,
    float* __restrict__ q_o, ushort* __restrict__ k_o, ushort* __restrict__ v_o,
    float* __restrict__ f_o, int M)
{
    __shared__ __align__(16) ushort As[128 * 32];
    __shared__ __align__(16) ushort Bs[128 * 32];

    const int tid  = threadIdx.x;
    const int w    = tid >> 6, lane = tid & 63;
    const int wr   = w >> 1,  wc   = w & 1;
    const int m0   = blockIdx.x * 128;
    const int n0   = blockIdx.y * 128;
    const int srow = tid >> 2;
    const int skb  = (tid & 3) * 8;

    f32x4 acc[4][4];
#pragma unroll
    for (int m = 0; m < 4; m++)
#pragma unroll
        for (int n = 0; n < 4; n++) acc[m][n] = (f32x4)0.f;

    int ra0 = m0 + srow;       if (ra0 >= M) ra0 = M - 1;
    int ra1 = m0 + 64 + srow;  if (ra1 >= M) ra1 = M - 1;
    const int rb0 = n0 + srow, rb1 = n0 + 64 + srow;

    for (int k0 = 0; k0 < EMB; k0 += 32) {
        gl_lds16(A + (size_t)ra0 * EMB + k0 + skb, As + (w * 512));
        gl_lds16(A + (size_t)ra1 * EMB + k0 + skb, As + (2048 + w * 512));
        gl_lds16(W + (size_t)rb0 * EMB + k0 + skb, Bs + (w * 512));
        gl_lds16(W + (size_t)rb1 * EMB + k0 + skb, Bs + (2048 + w * 512));
        __syncthreads();

        bf16x8 af[4], bfr[4];
#pragma unroll
        for (int m = 0; m < 4; m++)
            af[m] = *(const bf16x8*)&As[(wr * 64 + m * 16 + (lane & 15)) * 32 + (lane >> 4) * 8];
#pragma unroll
        for (int n = 0; n < 4; n++)
            bfr[n] = *(const bf16x8*)&Bs[(wc * 64 + n * 16 + (lane & 15)) * 32 + (lane >> 4) * 8];
#pragma unroll
        for (int m = 0; m < 4; m++)
#pragma unroll
            for (int n = 0; n < 4; n++)
                acc[m][n] = __builtin_amdgcn_mfma_f32_16x16x32_bf16(af[m], bfr[n], acc[m][n], 0, 0, 0);
        __syncthreads();
    }

    const int nr = (MODE == 0) ? (n0 % EMB) : n0;
    const int mat = (MODE == 0) ? (n0 / EMB) : 0;
    const float* bias = (mat == 0) ? b0 : (mat == 1) ? b1 : b2;

#pragma unroll
    for (int m = 0; m < 4; m++) {
#pragma unroll
        for (int r = 0; r < 4; r++) {
            const int gm = m0 + wr * 64 + m * 16 + (lane >> 4) * 4 + r;
            if (gm >= M) continue;
            const int bb = gm / SEQ, ss = gm - bb * SEQ;
#pragma unroll
            for (int n = 0; n < 4; n++) {
                const int col = nr + wc * 64 + n * 16 + (lane & 15);
                const float v = acc[m][n][r] + bias[col];
                if (MODE == 0) {
                    const size_t oi = (((size_t)bb * NH + (col >> 6)) * SEQ + ss) * HD + (col & 63);
                    if (mat == 0)      q_o[oi] = v;
                    else if (mat == 1) k_o[oi] = f2bf(v);
                    else               v_o[oi] = f2bf(v);
                } else {
                    f_o[(size_t)gm * EMB + col] = v;
                }
            }
        }
    }
}

// ---------------------------------------------------------------------------
// Fused attention — r7 structure (256 thr, 4 waves), LDS shrunk to 63.7 KB
// so 2 blocks/CU co-reside (VGPR 256 allows 8 waves/CU):
//   K_s bf16 (xor-swizzled), rx/ry bf16, V streamed bf16 from global
//   (25 KB slice/block -> L1-resident), p/h fp32.
// ---------------------------------------------------------------------------
__global__ __launch_bounds__(256) void attn_k(
    const float* __restrict__ xq, const ushort* __restrict__ xk, const ushort* __restrict__ xv,
    const float* __restrict__ q_tab_x, const float* __restrict__ q_tab_y,
    const float* __restrict__ v_tab_x, const float* __restrict__ v_tab_y,
    const int* __restrict__ x_dist, const int* __restrict__ y_dist,
    ushort* __restrict__ ao)
{
    __shared__ __align__(16) ushort K_s[SEQ * HD];    // 25216 B bf16, chunk^=(k&7)
    __shared__ ushort rx_s[SEQ * NE];                 // 11032 B
    __shared__ ushort ry_s[SEQ * NE];                 // 11032 B
    __shared__ float  p_s[4][4][200];                 // 12800 B
    __shared__ float  h_s[4][4][2 * NE];              // 3584 B  -> 63664 total

    const int bh = blockIdx.x;
    const int b  = bh / NH;
    const int h  = bh % NH;
    const float*  __restrict__ xq_r = xq + (size_t)bh * SEQ * HD;
    const ushort* __restrict__ xk_r = xk + (size_t)bh * SEQ * HD;
    const ushort* __restrict__ xv_r = xv + (size_t)bh * SEQ * HD;

    const int tid  = threadIdx.x;
    const int w    = tid >> 6;
    const int lane = tid & 63;

    // ---- stage K (bf16, xor-swizzled 16B chunks) ----
    for (int idx = tid; idx < SEQ * 8; idx += 256) {
        const int k = idx >> 3, c = idx & 7;
        uint4 kv = *(const uint4*)(xk_r + k * HD + c * 8);
        *(uint4*)&K_s[k * HD + ((c ^ (k & 7)) << 3)] = kv;
    }
    // ---- r_x/r_y: r[q][e] = sum_{d<32} xq[q,d]*tab[e,d]  (bf16 store) ----
    for (int o = tid; o < SEQ * 2 * NE; o += 256) {
        const int q = o / (2 * NE);
        const int j = o % (2 * NE);
        const int isx = (j < NE);
        const int e = isx ? j : (j - NE);
        const float* qrow = xq_r + q * HD + (isx ? 0 : 32);
        const float* tab  = (isx ? q_tab_x : q_tab_y) + e * 32;
        float acc = 0.f;
#pragma unroll
        for (int d = 0; d < 32; d += 4) {
            float4 a = *(const float4*)(qrow + d);
            float4 t = *(const float4*)(tab + d);
            acc += a.x * t.x + a.y * t.y + a.z * t.z + a.w * t.w;
        }
        (isx ? rx_s : ry_s)[q * NE + e] = f2bf(acc);
    }
    __syncthreads();

    const int k0 = lane, k1 = lane + 64, k2 = lane + 128, k3 = lane + 192;
    const bool v3 = (k3 < SEQ);
    const int k3c = v3 ? k3 : 0;
    const int swz = (lane & 7);   // k0..k3 differ by 64 -> same low-3 bits

    for (int q0 = w * 4; q0 < SEQ; q0 += 16) {
        // ---------------- QK^T for 4 query rows ----------------
        float acc[4][4];
#pragma unroll
        for (int qq = 0; qq < 4; qq++)
#pragma unroll
            for (int s = 0; s < 4; s++) acc[qq][s] = 0.f;

        const float* qps[4];
#pragma unroll
        for (int qq = 0; qq < 4; qq++) {
            int qi = q0 + qq; if (qi > SEQ - 1) qi = SEQ - 1;
            qps[qq] = xq_r + qi * HD;
        }
#pragma unroll
        for (int db = 0; db < 8; db++) {
            const int sc = (db ^ swz) << 3;   // ushort offset of 16B chunk
            f32x8 kf0 = unpk8v(*(const uint4*)&K_s[k0  * HD + sc]);
            f32x8 kf1 = unpk8v(*(const uint4*)&K_s[k1  * HD + sc]);
            f32x8 kf2 = unpk8v(*(const uint4*)&K_s[k2  * HD + sc]);
            f32x8 kf3 = unpk8v(*(const uint4*)&K_s[k3c * HD + sc]);
#pragma unroll
            for (int qq = 0; qq < 4; qq++) {
                const float4 qa = *(const float4*)(qps[qq] + db * 8);
                const float4 qb = *(const float4*)(qps[qq] + db * 8 + 4);
                acc[qq][0] = fmaf(qa.x, kf0[0], acc[qq][0]); acc[qq][0] = fmaf(qa.y, kf0[1], acc[qq][0]);
                acc[qq][0] = fmaf(qa.z, kf0[2], acc[qq][0]); acc[qq][0] = fmaf(qa.w, kf0[3], acc[qq][0]);
                acc[qq][0] = fmaf(qb.x, kf0[4], acc[qq][0]); acc[qq][0] = fmaf(qb.y, kf0[5], acc[qq][0]);
                acc[qq][0] = fmaf(qb.z, kf0[6], acc[qq][0]); acc[qq][0] = fmaf(qb.w, kf0[7], acc[qq][0]);
                acc[qq][1] = fmaf(qa.x, kf1[0], acc[qq][1]); acc[qq][1] = fmaf(qa.y, kf1[1], acc[qq][1]);
                acc[qq][1] = fmaf(qa.z, kf1[2], acc[qq][1]); acc[qq][1] = fmaf(qa.w, kf1[3], acc[qq][1]);
                acc[qq][1] = fmaf(qb.x, kf1[4], acc[qq][1]); acc[qq][1] = fmaf(qb.y, kf1[5], acc[qq][1]);
                acc[qq][1] = fmaf(qb.z, kf1[6], acc[qq][1]); acc[qq][1] = fmaf(qb.w, kf1[7], acc[qq][1]);
                acc[qq][2] = fmaf(qa.x, kf2[0], acc[qq][2]); acc[qq][2] = fmaf(qa.y, kf2[1], acc[qq][2]);
                acc[qq][2] = fmaf(qa.z, kf2[2], acc[qq][2]); acc[qq][2] = fmaf(qa.w, kf2[3], acc[qq][2]);
                acc[qq][2] = fmaf(qb.x, kf2[4], acc[qq][2]); acc[qq][2] = fmaf(qb.y, kf2[5], acc[qq][2]);
                acc[qq][2] = fmaf(qb.z, kf2[6], acc[qq][2]); acc[qq][2] = fmaf(qb.w, kf2[7], acc[qq][2]);
                acc[qq][3] = fmaf(qa.x, kf3[0], acc[qq][3]); acc[qq][3] = fmaf(qa.y, kf3[1], acc[qq][3]);
                acc[qq][3] = fmaf(qa.z, kf3[2], acc[qq][3]); acc[qq][3] = fmaf(qa.w, kf3[3], acc[qq][3]);
                acc[qq][3] = fmaf(qb.x, kf3[4], acc[qq][3]); acc[qq][3] = fmaf(qb.y, kf3[5], acc[qq][3]);
                acc[qq][3] = fmaf(qb.z, kf3[6], acc[qq][3]); acc[qq][3] = fmaf(qb.w, kf3[7], acc[qq][3]);
            }
        }

        // ---------------- softmax + histogram per query ----------------
#pragma unroll
        for (int qq = 0; qq < 4; qq++) {
            const int q = q0 + qq;
            if (q < SEQ) {
                const int* xd = x_dist + q * SEQ;
                const int* yd = y_dist + q * SEQ;
                const int e0x = xd[k0], e1x = xd[k1], e2x = xd[k2], e3x = xd[k3c];
                const int e0y = yd[k0], e1y = yd[k1], e2y = yd[k2], e3y = yd[k3c];
                const ushort* rx = rx_s + q * NE;
                const ushort* ry = ry_s + q * NE;
                const float l0 = (acc[qq][0] + bfl(rx[e0x]) + bfl(ry[e0y])) * 0.125f;
                const float l1 = (acc[qq][1] + bfl(rx[e1x]) + bfl(ry[e1y])) * 0.125f;
                const float l2 = (acc[qq][2] + bfl(rx[e2x]) + bfl(ry[e2y])) * 0.125f;
                const float l3 = v3 ? (acc[qq][3] + bfl(rx[e3x]) + bfl(ry[e3y])) * 0.125f : -1e30f;
                float mx = fmaxf(fmaxf(l0, l1), fmaxf(l2, l3));
#pragma unroll
                for (int off = 32; off >= 1; off >>= 1) mx = fmaxf(mx, __shfl_xor(mx, off));
                float p0 = __expf(l0 - mx), p1 = __expf(l1 - mx), p2 = __expf(l2 - mx);
                float p3 = v3 ? __expf(l3 - mx) : 0.f;
                float sm = p0 + p1 + p2 + p3;
#pragma unroll
                for (int off = 32; off >= 1; off >>= 1) sm += __shfl_xor(sm, off);
                const float inv = 1.f / sm;
                p0 *= inv; p1 *= inv; p2 *= inv; p3 *= inv;

                if (lane < 2 * NE) h_s[w][qq][lane] = 0.f;
                p_s[w][qq][k0] = p0;
                p_s[w][qq][k1] = p1;
                p_s[w][qq][k2] = p2;
                if (v3) p_s[w][qq][k3] = p3;
                atomicAdd(&h_s[w][qq][e0x], p0);
                atomicAdd(&h_s[w][qq][NE + e0y], p0);
                atomicAdd(&h_s[w][qq][e1x], p1);
                atomicAdd(&h_s[w][qq][NE + e1y], p1);
                atomicAdd(&h_s[w][qq][e2x], p2);
                atomicAdd(&h_s[w][qq][NE + e2y], p2);
                if (v3) {
                    atomicAdd(&h_s[w][qq][e3x], p3);
                    atomicAdd(&h_s[w][qq][NE + e3y], p3);
                }
            }
        }

        // ---------------- PV (V bf16 streamed from global/L1) + v_pos --------
        const int d4 = (lane & 15) * 4;
        const int kk = lane >> 4;
        float4 o4[4];
#pragma unroll
        for (int qq = 0; qq < 4; qq++) o4[qq] = make_float4(0.f, 0.f, 0.f, 0.f);

        for (int kb = 0; kb < SEQ; kb += 4) {
            const int k  = kb + kk;
            const bool ok = (k < SEQ);
            const int kc = ok ? k : 0;
            uint2 vv = *(const uint2*)(xv_r + kc * HD + d4);
            const float vf0 = bfl(vv.x), vf1 = bfh(vv.x), vf2 = bfl(vv.y), vf3 = bfh(vv.y);
#pragma unroll
            for (int qq = 0; qq < 4; qq++) {
                const float p = ok ? p_s[w][qq][k] : 0.f;
                o4[qq].x = fmaf(p, vf0, o4[qq].x);
                o4[qq].y = fmaf(p, vf1, o4[qq].y);
                o4[qq].z = fmaf(p, vf2, o4[qq].z);
                o4[qq].w = fmaf(p, vf3, o4[qq].w);
            }
        }
#pragma unroll
        for (int qq = 0; qq < 4; qq++) {
            o4[qq].x += __shfl_xor(o4[qq].x, 16); o4[qq].x += __shfl_xor(o4[qq].x, 32);
            o4[qq].y += __shfl_xor(o4[qq].y, 16); o4[qq].y += __shfl_xor(o4[qq].y, 32);
            o4[qq].z += __shfl_xor(o4[qq].z, 16); o4[qq].z += __shfl_xor(o4[qq].z, 32);
            o4[qq].w += __shfl_xor(o4[qq].w, 16); o4[qq].w += __shfl_xor(o4[qq].w, 32);
        }

        if (kk == 0) {
            const bool isx = (d4 < 32);
            const int dl = d4 & 31;
            const float* tab = (isx ? v_tab_x : v_tab_y) + dl;
#pragma unroll
            for (int e = 0; e < NE; e++) {
                float4 tv = *(const float4*)(tab + e * 32);
#pragma unroll
                for (int qq = 0; qq < 4; qq++) {
                    const float hh = h_s[w][qq][(isx ? 0 : NE) + e];
                    o4[qq].x = fmaf(hh, tv.x, o4[qq].x);
                    o4[qq].y = fmaf(hh, tv.y, o4[qq].y);
                    o4[qq].z = fmaf(hh, tv.z, o4[qq].z);
                    o4[qq].w = fmaf(hh, tv.w, o4[qq].w);
                }
            }
#pragma unroll
            for (int qq = 0; qq < 4; qq++) {
                const int q = q0 + qq;
                if (q < SEQ) {
                    unsigned r0 = ((unsigned)f2bf(o4[qq].y) << 16) | f2bf(o4[qq].x);
                    unsigned r1 = ((unsigned)f2bf(o4[qq].w) << 16) | f2bf(o4[qq].z);
                    uint2 pk = { r0, r1 };
                    // (b, s, h, d) = row-major (M, EMB) for the output projection
                    *(uint2*)(ao + (((size_t)b * SEQ + q) * NH + h) * HD + d4) = pk;
                }
            }
        }
    }
}

extern "C" void kernel_launch(void* const* d_in, const int* in_sizes, int n_in,
                              void* d_out, int out_size, void* d_ws, size_t ws_size,
                              hipStream_t stream) {
    const float* x       = (const float*)d_in[0];
    const float* Wq      = (const float*)d_in[1];
    const float* bq      = (const float*)d_in[2];
    const float* Wk      = (const float*)d_in[3];
    const float* bk      = (const float*)d_in[4];
    const float* Wv      = (const float*)d_in[5];
    const float* bv      = (const float*)d_in[6];
    const float* Wo      = (const float*)d_in[7];
    const float* bo      = (const float*)d_in[8];
    const float* q_tab_x = (const float*)d_in[9];
    const float* q_tab_y = (const float*)d_in[10];
    const float* v_tab_x = (const float*)d_in[11];
    const float* v_tab_y = (const float*)d_in[12];
    const int*   x_dist  = (const int*)d_in[13];
    const int*   y_dist  = (const int*)d_in[14];
    float* out = (float*)d_out;

    const int M  = in_sizes[0] / EMB;   // 12608
    const int Bc = M / SEQ;             // 64

    // ws carve: xb | wqkv | wob (bf16) | qf (f32) | kb | vb | ao (bf16)
    ushort* xb   = (ushort*)d_ws;
    ushort* wqkv = xb   + (size_t)M * EMB;
    ushort* wob  = wqkv + (size_t)3 * EMB * EMB;
    float*  qf   = (float*)(wob + (size_t)EMB * EMB);
    ushort* kb   = (ushort*)(qf + (size_t)M * EMB);
    ushort* vb   = kb + (size_t)M * EMB;
    ushort* aob  = vb + (size_t)M * EMB;

    const int n4x = M * EMB / 4;
    cvt_k<<<dim3((n4x + 255) / 256), dim3(256), 0, stream>>>(x, xb, n4x);
    cvt_w4<<<dim3(2304), dim3(256), 0, stream>>>(Wq, Wk, Wv, Wo, wqkv, wob);

    mfma_gemm<0><<<dim3((M + 127) / 128, 18), dim3(256), 0, stream>>>(
        xb, wqkv, bq, bk, bv, qf, kb, vb, nullptr, M);

    attn_k<<<dim3(Bc * NH), dim3(256), 0, stream>>>(qf, kb, vb, q_tab_x, q_tab_y,
                                                    v_tab_x, v_tab_y, x_dist, y_dist, aob);

    mfma_gemm<1><<<dim3((M + 127) / 128, 6), dim3(256), 0, stream>>>(
        aob, wob, bo, bo, bo, nullptr, nullptr, nullptr, out, M);
}

// Round 9
// 741.981 us; speedup vs baseline: 1.7505x; 1.7505x over previous
//
#include <hip/hip_runtime.h>
#include <math.h>

#define SEQ 197
#define EMB 768
#define NH  12
#define HD  64
#define NE  28
#define SK  208   // padded K rows (13 tiles of 16)
#define VP  232   // padded row length (k) for VT_s / P_s  (bank-friendly, >=224)
#define HP  57    // padded histogram row

typedef __attribute__((ext_vector_type(8))) __bf16 bf16x8;
typedef __attribute__((ext_vector_type(4))) float  f32x4;
typedef __attribute__((ext_vector_type(8))) float  f32x8;

__device__ __forceinline__ unsigned short f2bf(float f) {
    unsigned u = __float_as_uint(f);
    u += 0x7fffu + ((u >> 16) & 1u);
    return (unsigned short)(u >> 16);
}
__device__ __forceinline__ float bfl(unsigned u) { return __uint_as_float(u << 16); }
__device__ __forceinline__ float bfh(unsigned u) { return __uint_as_float(u & 0xffff0000u); }
__device__ __forceinline__ f32x8 unpk8v(uint4 v) {
    f32x8 r;
    r[0] = bfl(v.x); r[1] = bfh(v.x); r[2] = bfl(v.y); r[3] = bfh(v.y);
    r[4] = bfl(v.z); r[5] = bfh(v.z); r[6] = bfl(v.w); r[7] = bfh(v.w);
    return r;
}

__device__ __forceinline__ void gl_lds16(const ushort* g, ushort* l) {
    __builtin_amdgcn_global_load_lds(
        (const __attribute__((address_space(1))) unsigned int*)g,
        (__attribute__((address_space(3))) unsigned int*)l, 16, 0, 0);
}

// ---------------------------------------------------------------------------
// prep kernels
// ---------------------------------------------------------------------------
__global__ void cvt_k(const float* __restrict__ src, ushort* __restrict__ dst, int n4) {
    int i = blockIdx.x * 256 + threadIdx.x;
    if (i < n4) {
        float4 v = ((const float4*)src)[i];
        ushort4 o = { f2bf(v.x), f2bf(v.y), f2bf(v.z), f2bf(v.w) };
        ((ushort4*)dst)[i] = o;
    }
}

__global__ void cvt_w4(const float* __restrict__ wq, const float* __restrict__ wk,
                       const float* __restrict__ wv, const float* __restrict__ wo,
                       ushort* __restrict__ wqkv, ushort* __restrict__ wob) {
    int i = blockIdx.x * 256 + threadIdx.x;          // 4 * 147456 total
    if (i >= 4 * 147456) return;
    int seg = i / 147456, r = i - seg * 147456;
    const float* s = (seg == 0) ? wq : (seg == 1) ? wk : (seg == 2) ? wv : wo;
    float4 v = ((const float4*)s)[r];
    ushort4 o = { f2bf(v.x), f2bf(v.y), f2bf(v.z), f2bf(v.w) };
    if (seg < 3) ((ushort4*)wqkv)[(size_t)seg * 147456 + r] = o;
    else         ((ushort4*)wob)[r] = o;
}

__global__ void pack_dist(const int* __restrict__ xd, const int* __restrict__ yd,
                          int* __restrict__ xy, int n) {
    int i = blockIdx.x * 256 + threadIdx.x;
    if (i < n) xy[i] = (xd[i] & 0xffff) | (yd[i] << 16);
}

// ---------------------------------------------------------------------------
// bf16 MFMA GEMM (m97 pattern).
// MODE 0: A=x_bf16, W=packed Wqkv; q,k,v -> bf16 (b,h,s,d) scatter.
// MODE 1: A=attn_out bf16, W=Wo; out -> fp32 row-major (M,768).
// ---------------------------------------------------------------------------
template<int MODE>
__global__ __launch_bounds__(256, 2) void mfma_gemm(
    const ushort* __restrict__ A, const ushort* __restrict__ W,
    const float* __restrict__ b0, const float* __restrict__ b1, const float* __restrict__ b2,
    ushort* __restrict__ q_o, ushort* __restrict__ k_o, ushort* __restrict__ v_o,
    float* __restrict__ f_o, int M)
{
    __shared__ __align__(16) ushort As[128 * 32];
    __shared__ __align__(16) ushort Bs[128 * 32];

    const int tid  = threadIdx.x;
    const int w    = tid >> 6, lane = tid & 63;
    const int wr   = w >> 1,  wc   = w & 1;
    const int m0   = blockIdx.x * 128;
    const int n0   = blockIdx.y * 128;
    const int srow = tid >> 2;
    const int skb  = (tid & 3) * 8;

    f32x4 acc[4][4];
#pragma unroll
    for (int m = 0; m < 4; m++)
#pragma unroll
        for (int n = 0; n < 4; n++) acc[m][n] = (f32x4)0.f;

    int ra0 = m0 + srow;       if (ra0 >= M) ra0 = M - 1;
    int ra1 = m0 + 64 + srow;  if (ra1 >= M) ra1 = M - 1;
    const int rb0 = n0 + srow, rb1 = n0 + 64 + srow;

    for (int k0 = 0; k0 < EMB; k0 += 32) {
        gl_lds16(A + (size_t)ra0 * EMB + k0 + skb, As + (w * 512));
        gl_lds16(A + (size_t)ra1 * EMB + k0 + skb, As + (2048 + w * 512));
        gl_lds16(W + (size_t)rb0 * EMB + k0 + skb, Bs + (w * 512));
        gl_lds16(W + (size_t)rb1 * EMB + k0 + skb, Bs + (2048 + w * 512));
        __syncthreads();

        bf16x8 af[4], bfr[4];
#pragma unroll
        for (int m = 0; m < 4; m++)
            af[m] = *(const bf16x8*)&As[(wr * 64 + m * 16 + (lane & 15)) * 32 + (lane >> 4) * 8];
#pragma unroll
        for (int n = 0; n < 4; n++)
            bfr[n] = *(const bf16x8*)&Bs[(wc * 64 + n * 16 + (lane & 15)) * 32 + (lane >> 4) * 8];
#pragma unroll
        for (int m = 0; m < 4; m++)
#pragma unroll
            for (int n = 0; n < 4; n++)
                acc[m][n] = __builtin_amdgcn_mfma_f32_16x16x32_bf16(af[m], bfr[n], acc[m][n], 0, 0, 0);
        __syncthreads();
    }

    const int nr = (MODE == 0) ? (n0 % EMB) : n0;
    const int mat = (MODE == 0) ? (n0 / EMB) : 0;
    const float* bias = (mat == 0) ? b0 : (mat == 1) ? b1 : b2;
    ushort* dst = (mat == 0) ? q_o : (mat == 1) ? k_o : v_o;

#pragma unroll
    for (int m = 0; m < 4; m++) {
#pragma unroll
        for (int r = 0; r < 4; r++) {
            const int gm = m0 + wr * 64 + m * 16 + (lane >> 4) * 4 + r;
            if (gm >= M) continue;
            const int bb = gm / SEQ, ss = gm - bb * SEQ;
#pragma unroll
            for (int n = 0; n < 4; n++) {
                const int col = nr + wc * 64 + n * 16 + (lane & 15);
                const float v = acc[m][n][r] + bias[col];
                if (MODE == 0) {
                    dst[(((size_t)bb * NH + (col >> 6)) * SEQ + ss) * HD + (col & 63)] = f2bf(v);
                } else {
                    f_o[(size_t)gm * EMB + col] = v;
                }
            }
        }
    }
}

// ---------------------------------------------------------------------------
// MFMA fused attention. One block per (b,h), 256 thr / 4 waves.
// QK^T and PV on matrix cores (same frag conventions as mfma_gemm, which is
// reference-verified). Softmax + rel-pos + histogram on VALU in C-layout:
//   C row (q_local) = (lane>>4)*4 + r ; C col = lane&15.
// K_s bf16 swizzled [208][64]; VT_s = V transposed [64][232] (pad 232);
// P_s per-wave [16][232] bf16 (pads zeroed once); h_s per-wave f32.
// No __syncthreads in the main loop — waves independent.
// ---------------------------------------------------------------------------
__global__ __launch_bounds__(256) void attn_mfma(
    const ushort* __restrict__ xq, const ushort* __restrict__ xk, const ushort* __restrict__ xv,
    const float* __restrict__ q_tab_x, const float* __restrict__ q_tab_y,
    const float* __restrict__ v_tab_x, const float* __restrict__ v_tab_y,
    const int* __restrict__ xy_dist,
    ushort* __restrict__ ao)
{
    __shared__ __align__(16) ushort K_s[SK * HD];       // 26624 B
    __shared__ __align__(16) ushort VT_s[HD * VP];      // 29696 B
    __shared__ __align__(16) ushort P_s[4 * 16 * VP];   // 29696 B
    __shared__ ushort rx_s[SEQ * NE];                   // 11032 B
    __shared__ ushort ry_s[SEQ * NE];                   // 11032 B
    __shared__ float  h_s[4][16][HP];                   // 14592 B -> 122672 total

    const int bh = blockIdx.x;
    const int b  = bh / NH;
    const int h  = bh % NH;
    const size_t base = (size_t)bh * SEQ * HD;
    const int tid = threadIdx.x;
    const int w = tid >> 6, lane = tid & 63;
    const int g = lane >> 4, c15 = lane & 15;

    // ---- stage K (bf16, swizzled 16B chunks; pad rows zero) ----
    for (int idx = tid; idx < SK * 8; idx += 256) {
        const int r = idx >> 3, c = idx & 7;
        uint4 v = make_uint4(0, 0, 0, 0);
        if (r < SEQ) v = *(const uint4*)(xk + base + r * HD + c * 8);
        *(uint4*)&K_s[r * HD + ((c ^ (r & 7)) << 3)] = v;
    }
    // ---- VT pad columns zero (k in [197,232)) ----
    for (int idx = tid; idx < HD * (VP - SEQ); idx += 256) {
        const int d = idx / (VP - SEQ), k = SEQ + idx - d * (VP - SEQ);
        VT_s[d * VP + k] = 0;
    }
    // ---- P zero all (pads must stay 0 across iterations) ----
    for (int idx = tid; idx < 4 * 16 * VP / 8; idx += 256)
        *(uint4*)&P_s[idx * 8] = make_uint4(0, 0, 0, 0);
    // ---- VT transpose write: VT[d][k] = V[k][d] (disjoint from pad region) ----
    for (int idx = tid; idx < SEQ * 8; idx += 256) {
        const int k = idx >> 3, db = idx & 7;
        uint4 v = *(const uint4*)(xv + base + k * HD + db * 8);
        ushort* col = &VT_s[(db * 8) * VP + k];
        col[0 * VP] = (ushort)(v.x); col[1 * VP] = (ushort)(v.x >> 16);
        col[2 * VP] = (ushort)(v.y); col[3 * VP] = (ushort)(v.y >> 16);
        col[4 * VP] = (ushort)(v.z); col[5 * VP] = (ushort)(v.z >> 16);
        col[6 * VP] = (ushort)(v.w); col[7 * VP] = (ushort)(v.w >> 16);
    }
    // ---- rx/ry: r[q][e] = sum_{d<32} xq[q,d]*tab[e,d] (bf16) ----
    for (int o = tid; o < SEQ * 2 * NE; o += 256) {
        const int q = o / (2 * NE);
        const int j = o - q * (2 * NE);
        const int isx = (j < NE);
        const int e = isx ? j : (j - NE);
        const ushort* qrow = xq + base + q * HD + (isx ? 0 : 32);
        const float*  tab  = (isx ? q_tab_x : q_tab_y) + e * 32;
        float acc = 0.f;
#pragma unroll
        for (int d = 0; d < 32; d += 8) {
            f32x8 qf = unpk8v(*(const uint4*)(qrow + d));
            float4 t0 = *(const float4*)(tab + d);
            float4 t1 = *(const float4*)(tab + d + 4);
            acc += qf[0]*t0.x + qf[1]*t0.y + qf[2]*t0.z + qf[3]*t0.w
                 + qf[4]*t1.x + qf[5]*t1.y + qf[6]*t1.z + qf[7]*t1.w;
        }
        (isx ? rx_s : ry_s)[q * NE + e] = f2bf(acc);
    }
    __syncthreads();

    // ---- main loop: wave w owns q-tiles {w, w+4, w+8, w+12} ----
    for (int qt = w; qt < 13; qt += 4) {
        const int qrow = qt * 16 + c15;
        const int qld  = (qrow < SEQ) ? qrow : (SEQ - 1);
        const bf16x8 qa0 = *(const bf16x8*)(xq + base + (size_t)qld * HD + g * 8);
        const bf16x8 qa1 = *(const bf16x8*)(xq + base + (size_t)qld * HD + 32 + g * 8);

        // QK^T: 13 k-tiles x 2 k-steps
        f32x4 acc[13];
#pragma unroll
        for (int kt = 0; kt < 13; kt++) {
            acc[kt] = (f32x4)0.f;
            const int kr = kt * 16 + c15;
            bf16x8 kf0 = *(const bf16x8*)&K_s[kr * HD + (((0 + g) ^ (kr & 7)) << 3)];
            bf16x8 kf1 = *(const bf16x8*)&K_s[kr * HD + (((4 + g) ^ (kr & 7)) << 3)];
            acc[kt] = __builtin_amdgcn_mfma_f32_16x16x32_bf16(qa0, kf0, acc[kt], 0, 0, 0);
            acc[kt] = __builtin_amdgcn_mfma_f32_16x16x32_bf16(qa1, kf1, acc[kt], 0, 0, 0);
        }

        // logits: + rel-pos, scale, mask; row max
        float mx[4] = {-3e38f, -3e38f, -3e38f, -3e38f};
#pragma unroll
        for (int kt = 0; kt < 13; kt++) {
            const int k  = kt * 16 + c15;
            const int kc = (k < SEQ) ? k : (SEQ - 1);
#pragma unroll
            for (int r = 0; r < 4; r++) {
                const int q  = qt * 16 + 4 * g + r;
                const int qg = (q < SEQ) ? q : (SEQ - 1);
                const int xy = xy_dist[qg * SEQ + kc];
                float l = (acc[kt][r] + bfl(rx_s[qg * NE + (xy & 0xffff)])
                                      + bfl(ry_s[qg * NE + (xy >> 16)])) * 0.125f;
                if (k >= SEQ) l = -3e38f;
                acc[kt][r] = l;
                mx[r] = fmaxf(mx[r], l);
            }
        }
#pragma unroll
        for (int r = 0; r < 4; r++) {
            mx[r] = fmaxf(mx[r], __shfl_xor(mx[r], 1));
            mx[r] = fmaxf(mx[r], __shfl_xor(mx[r], 2));
            mx[r] = fmaxf(mx[r], __shfl_xor(mx[r], 4));
            mx[r] = fmaxf(mx[r], __shfl_xor(mx[r], 8));
        }
        float sum[4] = {0.f, 0.f, 0.f, 0.f};
#pragma unroll
        for (int kt = 0; kt < 13; kt++)
#pragma unroll
            for (int r = 0; r < 4; r++) {
                const float p = __expf(acc[kt][r] - mx[r]);
                acc[kt][r] = p;
                sum[r] += p;
            }
#pragma unroll
        for (int r = 0; r < 4; r++) {
            sum[r] += __shfl_xor(sum[r], 1);
            sum[r] += __shfl_xor(sum[r], 2);
            sum[r] += __shfl_xor(sum[r], 4);
            sum[r] += __shfl_xor(sum[r], 8);
            sum[r] = 1.f / sum[r];
        }

        // zero this wave's histogram
        {
            float* hw = (float*)h_s[w];
            for (int i = lane; i < 16 * HP; i += 64) hw[i] = 0.f;
        }

        // normalize, write P (bf16), histogram atomics
#pragma unroll
        for (int kt = 0; kt < 13; kt++) {
            const int k  = kt * 16 + c15;
            const int kc = (k < SEQ) ? k : (SEQ - 1);
#pragma unroll
            for (int r = 0; r < 4; r++) {
                const float p = acc[kt][r] * sum[r];     // 0 for masked k
                P_s[(w * 16 + 4 * g + r) * VP + k] = f2bf(p);
                const int q  = qt * 16 + 4 * g + r;
                const int qg = (q < SEQ) ? q : (SEQ - 1);
                const int xy = xy_dist[qg * SEQ + kc];
                atomicAdd(&h_s[w][4 * g + r][xy & 0xffff], p);
                atomicAdd(&h_s[w][4 * g + r][NE + (xy >> 16)], p);
            }
        }

        // PV: O[q][d] = sum_k P[q][k] * VT[d][k]
        f32x4 o[4];
#pragma unroll
        for (int dt = 0; dt < 4; dt++) o[dt] = (f32x4)0.f;
#pragma unroll
        for (int ks = 0; ks < 7; ks++) {
            bf16x8 pf = *(const bf16x8*)&P_s[(w * 16 + c15) * VP + ks * 32 + g * 8];
#pragma unroll
            for (int dt = 0; dt < 4; dt++) {
                bf16x8 vf = *(const bf16x8*)&VT_s[(dt * 16 + c15) * VP + ks * 32 + g * 8];
                o[dt] = __builtin_amdgcn_mfma_f32_16x16x32_bf16(pf, vf, o[dt], 0, 0, 0);
            }
        }

        // v_pos (histogram @ tables) + store
#pragma unroll
        for (int dt = 0; dt < 4; dt++) {
            const int d = dt * 16 + c15;
            const float* tab = (d < 32) ? (v_tab_x + d) : (v_tab_y + d - 32);
            const int eb = (d < 32) ? 0 : NE;
#pragma unroll
            for (int r = 0; r < 4; r++) {
                const int q = qt * 16 + 4 * g + r;
                if (q < SEQ) {
                    float ov = o[dt][r];
#pragma unroll
                    for (int e = 0; e < NE; e++)
                        ov = fmaf(h_s[w][4 * g + r][eb + e], tab[e * 32], ov);
                    ao[((size_t)(b * SEQ + q)) * EMB + h * HD + d] = f2bf(ov);
                }
            }
        }
    }
}

extern "C" void kernel_launch(void* const* d_in, const int* in_sizes, int n_in,
                              void* d_out, int out_size, void* d_ws, size_t ws_size,
                              hipStream_t stream) {
    const float* x       = (const float*)d_in[0];
    const float* Wq      = (const float*)d_in[1];
    const float* bq      = (const float*)d_in[2];
    const float* Wk      = (const float*)d_in[3];
    const float* bk      = (const float*)d_in[4];
    const float* Wv      = (const float*)d_in[5];
    const float* bv      = (const float*)d_in[6];
    const float* Wo      = (const float*)d_in[7];
    const float* bo      = (const float*)d_in[8];
    const float* q_tab_x = (const float*)d_in[9];
    const float* q_tab_y = (const float*)d_in[10];
    const float* v_tab_x = (const float*)d_in[11];
    const float* v_tab_y = (const float*)d_in[12];
    const int*   x_dist  = (const int*)d_in[13];
    const int*   y_dist  = (const int*)d_in[14];
    float* out = (float*)d_out;

    const int M  = in_sizes[0] / EMB;   // 12608
    const int Bc = M / SEQ;             // 64

    // ws carve (bf16 = ushort): xb | wqkv | wob | xqb | xkb | xvb | aob | xyd
    ushort* xb   = (ushort*)d_ws;
    ushort* wqkv = xb   + (size_t)M * EMB;
    ushort* wob  = wqkv + (size_t)3 * EMB * EMB;
    ushort* xqb  = wob  + (size_t)EMB * EMB;
    ushort* xkb  = xqb  + (size_t)M * EMB;
    ushort* xvb  = xkb  + (size_t)M * EMB;
    ushort* aob  = xvb  + (size_t)M * EMB;
    int*    xyd  = (int*)(aob + (size_t)M * EMB);

    const int n4x = M * EMB / 4;
    cvt_k<<<dim3((n4x + 255) / 256), dim3(256), 0, stream>>>(x, xb, n4x);
    cvt_w4<<<dim3(2304), dim3(256), 0, stream>>>(Wq, Wk, Wv, Wo, wqkv, wob);
    pack_dist<<<dim3((SEQ * SEQ + 255) / 256), dim3(256), 0, stream>>>(
        x_dist, y_dist, xyd, SEQ * SEQ);

    mfma_gemm<0><<<dim3((M + 127) / 128, 18), dim3(256), 0, stream>>>(
        xb, wqkv, bq, bk, bv, xqb, xkb, xvb, nullptr, M);

    attn_mfma<<<dim3(Bc * NH), dim3(256), 0, stream>>>(
        xqb, xkb, xvb, q_tab_x, q_tab_y, v_tab_x, v_tab_y, xyd, aob);

    mfma_gemm<1><<<dim3((M + 127) / 128, 6), dim3(256), 0, stream>>>(
        aob, wob, bo, bo, bo, nullptr, nullptr, nullptr, out, M);
}

// Round 10
// 612.061 us; speedup vs baseline: 2.1221x; 1.2123x over previous
//
#include <hip/hip_runtime.h>
#include <math.h>

#define SEQ 197
#define EMB 768
#define NH  12
#define HD  64
#define NE  28
#define SK  208   // padded K rows (13 tiles of 16)
#define VP  232   // VT row length (k), padded
#define PP  224   // P row length (k), padded (PV reads exactly [0,224))
#define HP  60    // padded histogram row (f32, 16B-aligned rows)
#define NW  7     // waves per attn block
#define NT  448   // attn threads

typedef __attribute__((ext_vector_type(8))) __bf16 bf16x8;
typedef __attribute__((ext_vector_type(4))) float  f32x4;
typedef __attribute__((ext_vector_type(8))) float  f32x8;

__device__ __forceinline__ unsigned short f2bf(float f) {
    unsigned u = __float_as_uint(f);
    u += 0x7fffu + ((u >> 16) & 1u);
    return (unsigned short)(u >> 16);
}
__device__ __forceinline__ float bfl(unsigned u) { return __uint_as_float(u << 16); }

__device__ __forceinline__ void gl_lds16(const ushort* g, ushort* l) {
    __builtin_amdgcn_global_load_lds(
        (const __attribute__((address_space(1))) unsigned int*)g,
        (__attribute__((address_space(3))) unsigned int*)l, 16, 0, 0);
}

// ---------------------------------------------------------------------------
// prep kernels
// ---------------------------------------------------------------------------
__global__ void cvt_k(const float* __restrict__ src, ushort* __restrict__ dst, int n4) {
    int i = blockIdx.x * 256 + threadIdx.x;
    if (i < n4) {
        float4 v = ((const float4*)src)[i];
        ushort4 o = { f2bf(v.x), f2bf(v.y), f2bf(v.z), f2bf(v.w) };
        ((ushort4*)dst)[i] = o;
    }
}

__global__ void cvt_w4(const float* __restrict__ wq, const float* __restrict__ wk,
                       const float* __restrict__ wv, const float* __restrict__ wo,
                       ushort* __restrict__ wqkv, ushort* __restrict__ wob) {
    int i = blockIdx.x * 256 + threadIdx.x;          // 4 * 147456 total
    if (i >= 4 * 147456) return;
    int seg = i / 147456, r = i - seg * 147456;
    const float* s = (seg == 0) ? wq : (seg == 1) ? wk : (seg == 2) ? wv : wo;
    float4 v = ((const float4*)s)[r];
    ushort4 o = { f2bf(v.x), f2bf(v.y), f2bf(v.z), f2bf(v.w) };
    if (seg < 3) ((ushort4*)wqkv)[(size_t)seg * 147456 + r] = o;
    else         ((ushort4*)wob)[r] = o;
}

// Wr[row2][c] appended at wqkv rows [2304, 3072):
//   row2 = h*56+j ; j<28: sum_d Wq[h*64+d][c]*qtx[j][d]
//                   j>=28: sum_d Wq[h*64+32+d][c]*qty[j-28][d]
__global__ void wr_prep(const float* __restrict__ wq,
                        const float* __restrict__ qtx, const float* __restrict__ qty,
                        ushort* __restrict__ wqkv) {
    int i = blockIdx.x * 256 + threadIdx.x;          // 768*768
    if (i >= 768 * 768) return;
    int row2 = i / 768, c = i - row2 * 768;
    ushort* dst = wqkv + (size_t)(2304 + row2) * EMB + c;
    if (row2 >= 672) { *dst = 0; return; }
    int h = row2 / 56, j = row2 - h * 56;
    const int off = (j < 28) ? 0 : 32;
    const float* tab = (j < 28) ? (qtx + j * 32) : (qty + (j - 28) * 32);
    float acc = 0.f;
#pragma unroll
    for (int d = 0; d < 32; d++)
        acc += wq[(size_t)(h * 64 + off + d) * EMB + c] * tab[d];
    *dst = f2bf(acc);
}

__global__ void rbias_k(const float* __restrict__ bq,
                        const float* __restrict__ qtx, const float* __restrict__ qty,
                        float* __restrict__ rb) {
    int i = blockIdx.x * 256 + threadIdx.x;
    if (i >= 672) return;
    int h = i / 56, j = i - h * 56;
    const int off = (j < 28) ? 0 : 32;
    const float* tab = (j < 28) ? (qtx + j * 32) : (qty + (j - 28) * 32);
    float acc = 0.f;
#pragma unroll
    for (int d = 0; d < 32; d++)
        acc += bq[h * 64 + off + d] * tab[d];
    rb[i] = acc;
}

__global__ void pack_dist(const int* __restrict__ xd, const int* __restrict__ yd,
                          int* __restrict__ xy, int n) {
    int i = blockIdx.x * 256 + threadIdx.x;
    if (i < n) xy[i] = (xd[i] & 0xffff) | (yd[i] << 16);
}

// ---------------------------------------------------------------------------
// bf16 MFMA GEMM (m97 pattern).
// MODE 0: A=x_bf16, W=wqkv 3072 rows (q|k|v|Wr); cols<2304 -> bf16 (b,h,s,d);
//         cols [2304,2976) -> r_o[bh][q][56] bf16 (+rbias).
// MODE 1: A=attn_out bf16, W=Wo; out -> fp32 row-major (M,768).
// ---------------------------------------------------------------------------
template<int MODE>
__global__ __launch_bounds__(256, 2) void mfma_gemm(
    const ushort* __restrict__ A, const ushort* __restrict__ W,
    const float* __restrict__ b0, const float* __restrict__ b1, const float* __restrict__ b2,
    const float* __restrict__ rbias,
    ushort* __restrict__ q_o, ushort* __restrict__ k_o, ushort* __restrict__ v_o,
    ushort* __restrict__ r_o, float* __restrict__ f_o, int M)
{
    __shared__ __align__(16) ushort As[128 * 32];
    __shared__ __align__(16) ushort Bs[128 * 32];

    const int tid  = threadIdx.x;
    const int w    = tid >> 6, lane = tid & 63;
    const int wr   = w >> 1,  wc   = w & 1;
    const int m0   = blockIdx.x * 128;
    const int n0   = blockIdx.y * 128;
    const int srow = tid >> 2;
    const int skb  = (tid & 3) * 8;

    f32x4 acc[4][4];
#pragma unroll
    for (int m = 0; m < 4; m++)
#pragma unroll
        for (int n = 0; n < 4; n++) acc[m][n] = (f32x4)0.f;

    int ra0 = m0 + srow;       if (ra0 >= M) ra0 = M - 1;
    int ra1 = m0 + 64 + srow;  if (ra1 >= M) ra1 = M - 1;
    const int rb0 = n0 + srow, rb1 = n0 + 64 + srow;

    for (int k0 = 0; k0 < EMB; k0 += 32) {
        gl_lds16(A + (size_t)ra0 * EMB + k0 + skb, As + (w * 512));
        gl_lds16(A + (size_t)ra1 * EMB + k0 + skb, As + (2048 + w * 512));
        gl_lds16(W + (size_t)rb0 * EMB + k0 + skb, Bs + (w * 512));
        gl_lds16(W + (size_t)rb1 * EMB + k0 + skb, Bs + (2048 + w * 512));
        __syncthreads();

        bf16x8 af[4], bfr[4];
#pragma unroll
        for (int m = 0; m < 4; m++)
            af[m] = *(const bf16x8*)&As[(wr * 64 + m * 16 + (lane & 15)) * 32 + (lane >> 4) * 8];
#pragma unroll
        for (int n = 0; n < 4; n++)
            bfr[n] = *(const bf16x8*)&Bs[(wc * 64 + n * 16 + (lane & 15)) * 32 + (lane >> 4) * 8];
#pragma unroll
        for (int m = 0; m < 4; m++)
#pragma unroll
            for (int n = 0; n < 4; n++)
                acc[m][n] = __builtin_amdgcn_mfma_f32_16x16x32_bf16(af[m], bfr[n], acc[m][n], 0, 0, 0);
        __syncthreads();
    }

    const int mat = n0 / EMB;                // 0,1,2 = q,k,v ; 3 = rel region
    const int nr  = n0 % EMB;
    const float* bias = (mat == 0) ? b0 : (mat == 1) ? b1 : b2;
    ushort* dst = (mat == 0) ? q_o : (mat == 1) ? k_o : v_o;

#pragma unroll
    for (int m = 0; m < 4; m++) {
#pragma unroll
        for (int r = 0; r < 4; r++) {
            const int gm = m0 + wr * 64 + m * 16 + (lane >> 4) * 4 + r;
            if (gm >= M) continue;
            const int bb = gm / SEQ, ss = gm - bb * SEQ;
#pragma unroll
            for (int n = 0; n < 4; n++) {
                const int cl = wc * 64 + n * 16 + (lane & 15);
                if (MODE == 0) {
                    if (mat < 3) {
                        const int col = nr + cl;
                        const float v = acc[m][n][r] + bias[col];
                        dst[(((size_t)bb * NH + (col >> 6)) * SEQ + ss) * HD + (col & 63)] = f2bf(v);
                    } else {
                        const int col2 = (n0 - 2304) + cl;
                        if (col2 < 672) {
                            const int h2 = col2 / 56, j = col2 - h2 * 56;
                            const float v = acc[m][n][r] + rbias[col2];
                            r_o[((size_t)(bb * NH + h2) * SEQ + ss) * 56 + j] = f2bf(v);
                        }
                    }
                } else {
                    const int col = nr + cl;
                    f_o[(size_t)gm * EMB + col] = acc[m][n][r] + bias[col];
                }
            }
        }
    }
}

// ---------------------------------------------------------------------------
// MFMA fused attention. One block per (b,h), 448 thr / 7 waves (wave w owns
// q-tiles {w, w+7}). QK^T and PV on matrix cores (frag conventions verified
// in r9). rxy gathered from precomputed r_o (GEMM output) staged in LDS.
// Softmax: pass1 logits+max, pass2 exp-unnormalized + P write + histogram
// atomics; normalization deferred (1/sum folded into final store).
// LDS 155.4 KB -> 1 block/CU, 7 waves resident. No sync in main loop.
// ---------------------------------------------------------------------------
__global__ __launch_bounds__(NT) void attn_mfma(
    const ushort* __restrict__ xq, const ushort* __restrict__ xk, const ushort* __restrict__ xv,
    const ushort* __restrict__ rxy_g,
    const float* __restrict__ v_tab_x, const float* __restrict__ v_tab_y,
    const int* __restrict__ xy_dist,
    ushort* __restrict__ ao)
{
    __shared__ __align__(16) ushort K_s[SK * HD];        // 26624 B
    __shared__ __align__(16) ushort VT_s[HD * VP];       // 29696 B
    __shared__ __align__(16) ushort P_s[NW * 16 * PP];   // 50176 B
    __shared__ __align__(16) ushort rxy_s[SEQ * 56];     // 22064 B
    __shared__ float h_s[NW][16][HP];                    // 26880 B -> 155440

    const int bh = blockIdx.x;
    const int b  = bh / NH;
    const int h  = bh % NH;
    const size_t base = (size_t)bh * SEQ * HD;
    const int tid = threadIdx.x;
    const int w = tid >> 6, lane = tid & 63;
    const int g = lane >> 4, c15 = lane & 15;

    // ---- stage K (bf16, swizzled 16B chunks; pad rows zero) ----
    for (int idx = tid; idx < SK * 8; idx += NT) {
        const int r = idx >> 3, c = idx & 7;
        uint4 v = make_uint4(0, 0, 0, 0);
        if (r < SEQ) v = *(const uint4*)(xk + base + r * HD + c * 8);
        *(uint4*)&K_s[r * HD + ((c ^ (r & 7)) << 3)] = v;
    }
    // ---- VT pad columns zero ----
    for (int idx = tid; idx < HD * (VP - SEQ); idx += NT) {
        const int d = idx / (VP - SEQ), k = SEQ + idx - d * (VP - SEQ);
        VT_s[d * VP + k] = 0;
    }
    // ---- P zero all ----
    for (int idx = tid; idx < NW * 16 * PP / 8; idx += NT)
        *(uint4*)&P_s[idx * 8] = make_uint4(0, 0, 0, 0);
    // ---- VT transpose write ----
    for (int idx = tid; idx < SEQ * 8; idx += NT) {
        const int k = idx >> 3, db = idx & 7;
        uint4 v = *(const uint4*)(xv + base + k * HD + db * 8);
        ushort* col = &VT_s[(db * 8) * VP + k];
        col[0 * VP] = (ushort)(v.x); col[1 * VP] = (ushort)(v.x >> 16);
        col[2 * VP] = (ushort)(v.y); col[3 * VP] = (ushort)(v.y >> 16);
        col[4 * VP] = (ushort)(v.z); col[5 * VP] = (ushort)(v.z >> 16);
        col[6 * VP] = (ushort)(v.w); col[7 * VP] = (ushort)(v.w >> 16);
    }
    // ---- stage rxy (copy from GEMM output) ----
    {
        const uint4* src = (const uint4*)(rxy_g + (size_t)bh * SEQ * 56);
        for (int idx = tid; idx < SEQ * 56 / 8; idx += NT)
            *(uint4*)&rxy_s[idx * 8] = src[idx];
    }
    __syncthreads();

    // ---- main loop: wave w owns q-tiles {w, w+7} ----
    for (int qt = w; qt < 13; qt += NW) {
        const int qrow = qt * 16 + c15;
        const int qld  = (qrow < SEQ) ? qrow : (SEQ - 1);
        const bf16x8 qa0 = *(const bf16x8*)(xq + base + (size_t)qld * HD + g * 8);
        const bf16x8 qa1 = *(const bf16x8*)(xq + base + (size_t)qld * HD + 32 + g * 8);

        // QK^T
        f32x4 acc[13];
#pragma unroll
        for (int kt = 0; kt < 13; kt++) {
            acc[kt] = (f32x4)0.f;
            const int kr = kt * 16 + c15;
            bf16x8 kf0 = *(const bf16x8*)&K_s[kr * HD + (((0 + g) ^ (kr & 7)) << 3)];
            bf16x8 kf1 = *(const bf16x8*)&K_s[kr * HD + (((4 + g) ^ (kr & 7)) << 3)];
            acc[kt] = __builtin_amdgcn_mfma_f32_16x16x32_bf16(qa0, kf0, acc[kt], 0, 0, 0);
            acc[kt] = __builtin_amdgcn_mfma_f32_16x16x32_bf16(qa1, kf1, acc[kt], 0, 0, 0);
        }

        // pass 1: logits (+rel-pos, scale, mask) and row max
        float mx[4] = {-3e38f, -3e38f, -3e38f, -3e38f};
#pragma unroll
        for (int kt = 0; kt < 13; kt++) {
            const int k  = kt * 16 + c15;
            const int kc = (k < SEQ) ? k : (SEQ - 1);
#pragma unroll
            for (int r = 0; r < 4; r++) {
                const int q  = qt * 16 + 4 * g + r;
                const int qg = (q < SEQ) ? q : (SEQ - 1);
                const int xy = xy_dist[qg * SEQ + kc];
                float l = (acc[kt][r] + bfl(rxy_s[qg * 56 + (xy & 0xffff)])
                                      + bfl(rxy_s[qg * 56 + NE + (xy >> 16)])) * 0.125f;
                if (k >= SEQ) l = -3e38f;
                acc[kt][r] = l;
                mx[r] = fmaxf(mx[r], l);
            }
        }
#pragma unroll
        for (int r = 0; r < 4; r++) {
            mx[r] = fmaxf(mx[r], __shfl_xor(mx[r], 1));
            mx[r] = fmaxf(mx[r], __shfl_xor(mx[r], 2));
            mx[r] = fmaxf(mx[r], __shfl_xor(mx[r], 4));
            mx[r] = fmaxf(mx[r], __shfl_xor(mx[r], 8));
        }

        // zero this wave's histogram (same-wave LDS ordering; r9-validated)
        {
            float* hw = (float*)h_s[w];
            for (int i = lane; i < 16 * HP; i += 64) hw[i] = 0.f;
        }

        // pass 2: exp (unnormalized) + P write + histogram; accumulate sum
        float sum[4] = {0.f, 0.f, 0.f, 0.f};
#pragma unroll
        for (int kt = 0; kt < 13; kt++) {
            const int k  = kt * 16 + c15;
            const int kc = (k < SEQ) ? k : (SEQ - 1);
#pragma unroll
            for (int r = 0; r < 4; r++) {
                const int q  = qt * 16 + 4 * g + r;
                const int qg = (q < SEQ) ? q : (SEQ - 1);
                const float p = __expf(acc[kt][r] - mx[r]);     // 0 for masked k
                sum[r] += p;
                P_s[(w * 16 + 4 * g + r) * PP + k] = f2bf(p);
                const int xy = xy_dist[qg * SEQ + kc];
                atomicAdd(&h_s[w][4 * g + r][xy & 0xffff], p);
                atomicAdd(&h_s[w][4 * g + r][NE + (xy >> 16)], p);
            }
        }
        float inv[4];
#pragma unroll
        for (int r = 0; r < 4; r++) {
            sum[r] += __shfl_xor(sum[r], 1);
            sum[r] += __shfl_xor(sum[r], 2);
            sum[r] += __shfl_xor(sum[r], 4);
            sum[r] += __shfl_xor(sum[r], 8);
            inv[r] = 1.f / sum[r];
        }

        // PV (unnormalized): O[q][d] = sum_k P[q][k] * VT[d][k]
        f32x4 o[4];
#pragma unroll
        for (int dt = 0; dt < 4; dt++) o[dt] = (f32x4)0.f;
#pragma unroll
        for (int ks = 0; ks < 7; ks++) {
            bf16x8 pf = *(const bf16x8*)&P_s[(w * 16 + c15) * PP + ks * 32 + g * 8];
#pragma unroll
            for (int dt = 0; dt < 4; dt++) {
                bf16x8 vf = *(const bf16x8*)&VT_s[(dt * 16 + c15) * VP + ks * 32 + g * 8];
                o[dt] = __builtin_amdgcn_mfma_f32_16x16x32_bf16(pf, vf, o[dt], 0, 0, 0);
            }
        }

        // v_pos (unnormalized histogram @ tables) + scale + store
#pragma unroll
        for (int dt = 0; dt < 4; dt++) {
            const int d = dt * 16 + c15;
            const float* tab = (dt < 2) ? (v_tab_x + d) : (v_tab_y + d - 32);
            const int eb = (dt < 2) ? 0 : NE;
#pragma unroll
            for (int r = 0; r < 4; r++) {
                const int q = qt * 16 + 4 * g + r;
                if (q < SEQ) {
                    const float* hr = h_s[w][4 * g + r] + eb;
                    float sa = o[dt][r], sb = 0.f;
#pragma unroll
                    for (int e = 0; e < NE; e += 2) {
                        sa = fmaf(hr[e],     tab[e * 32],       sa);
                        sb = fmaf(hr[e + 1], tab[(e + 1) * 32], sb);
                    }
                    ao[((size_t)(b * SEQ + q)) * EMB + h * HD + d] = f2bf((sa + sb) * inv[r]);
                }
            }
        }
    }
}

extern "C" void kernel_launch(void* const* d_in, const int* in_sizes, int n_in,
                              void* d_out, int out_size, void* d_ws, size_t ws_size,
                              hipStream_t stream) {
    const float* x       = (const float*)d_in[0];
    const float* Wq      = (const float*)d_in[1];
    const float* bq      = (const float*)d_in[2];
    const float* Wk      = (const float*)d_in[3];
    const float* bk      = (const float*)d_in[4];
    const float* Wv      = (const float*)d_in[5];
    const float* bv      = (const float*)d_in[6];
    const float* Wo      = (const float*)d_in[7];
    const float* bo      = (const float*)d_in[8];
    const float* q_tab_x = (const float*)d_in[9];
    const float* q_tab_y = (const float*)d_in[10];
    const float* v_tab_x = (const float*)d_in[11];
    const float* v_tab_y = (const float*)d_in[12];
    const int*   x_dist  = (const int*)d_in[13];
    const int*   y_dist  = (const int*)d_in[14];
    float* out = (float*)d_out;

    const int M  = in_sizes[0] / EMB;   // 12608
    const int Bc = M / SEQ;             // 64

    // ws carve (bf16 = ushort)
    ushort* xb   = (ushort*)d_ws;                       // M*768
    ushort* wqkv = xb   + (size_t)M * EMB;              // 3072*768 (q|k|v|Wr)
    ushort* wob  = wqkv + (size_t)3072 * EMB;           // 768*768
    ushort* xqb  = wob  + (size_t)EMB * EMB;            // M*768
    ushort* xkb  = xqb  + (size_t)M * EMB;
    ushort* xvb  = xkb  + (size_t)M * EMB;
    ushort* aob  = xvb  + (size_t)M * EMB;
    ushort* r_o  = aob  + (size_t)M * EMB;              // 768*197*56
    float*  rbia = (float*)(r_o + (size_t)Bc * NH * SEQ * 56);
    int*    xyd  = (int*)(rbia + 672);

    const int n4x = M * EMB / 4;
    cvt_k<<<dim3((n4x + 255) / 256), dim3(256), 0, stream>>>(x, xb, n4x);
    cvt_w4<<<dim3(2304), dim3(256), 0, stream>>>(Wq, Wk, Wv, Wo, wqkv, wob);
    wr_prep<<<dim3(2304), dim3(256), 0, stream>>>(Wq, q_tab_x, q_tab_y, wqkv);
    rbias_k<<<dim3(3), dim3(256), 0, stream>>>(bq, q_tab_x, q_tab_y, rbia);
    pack_dist<<<dim3((SEQ * SEQ + 255) / 256), dim3(256), 0, stream>>>(
        x_dist, y_dist, xyd, SEQ * SEQ);

    mfma_gemm<0><<<dim3((M + 127) / 128, 24), dim3(256), 0, stream>>>(
        xb, wqkv, bq, bk, bv, rbia, xqb, xkb, xvb, r_o, nullptr, M);

    attn_mfma<<<dim3(Bc * NH), dim3(NT), 0, stream>>>(
        xqb, xkb, xvb, r_o, v_tab_x, v_tab_y, xyd, aob);

    mfma_gemm<1><<<dim3((M + 127) / 128, 6), dim3(256), 0, stream>>>(
        aob, wob, bo, bo, bo, nullptr, nullptr, nullptr, nullptr, nullptr, out, M);
}

// Round 11
// 590.551 us; speedup vs baseline: 2.1994x; 1.0364x over previous
//
#include <hip/hip_runtime.h>
#include <math.h>

#define SEQ 197
#define EMB 768
#define NH  12
#define HD  64
#define NE  28
#define SK  208   // padded K rows (13 tiles of 16)
#define VP  232   // VT row length (k), padded (2-way banks at stride 464B)
#define PP  232   // P row length (k), padded (224 was an 8-way conflict)
#define HP  68    // h row length (f32), padded (64 would be 16-way)
#define TP  68    // vtabT row length (ushort)
#define NW  7     // waves per attn block
#define NT  448   // attn threads

typedef __attribute__((ext_vector_type(8))) __bf16 bf16x8;
typedef __attribute__((ext_vector_type(4))) float  f32x4;

__device__ __forceinline__ unsigned short f2bf(float f) {
    unsigned u = __float_as_uint(f);
    u += 0x7fffu + ((u >> 16) & 1u);
    return (unsigned short)(u >> 16);
}
__device__ __forceinline__ float bfl(unsigned u) { return __uint_as_float(u << 16); }

__device__ __forceinline__ void gl_lds16(const ushort* g, ushort* l) {
    __builtin_amdgcn_global_load_lds(
        (const __attribute__((address_space(1))) unsigned int*)g,
        (__attribute__((address_space(3))) unsigned int*)l, 16, 0, 0);
}

// ---------------------------------------------------------------------------
// prep kernels
// ---------------------------------------------------------------------------
__global__ void cvt_k(const float* __restrict__ src, ushort* __restrict__ dst, int n4) {
    int i = blockIdx.x * 256 + threadIdx.x;
    if (i < n4) {
        float4 v = ((const float4*)src)[i];
        ushort4 o = { f2bf(v.x), f2bf(v.y), f2bf(v.z), f2bf(v.w) };
        ((ushort4*)dst)[i] = o;
    }
}

__global__ void cvt_w4(const float* __restrict__ wq, const float* __restrict__ wk,
                       const float* __restrict__ wv, const float* __restrict__ wo,
                       ushort* __restrict__ wqkv, ushort* __restrict__ wob) {
    int i = blockIdx.x * 256 + threadIdx.x;          // 4 * 147456 total
    if (i >= 4 * 147456) return;
    int seg = i / 147456, r = i - seg * 147456;
    const float* s = (seg == 0) ? wq : (seg == 1) ? wk : (seg == 2) ? wv : wo;
    float4 v = ((const float4*)s)[r];
    ushort4 o = { f2bf(v.x), f2bf(v.y), f2bf(v.z), f2bf(v.w) };
    if (seg < 3) ((ushort4*)wqkv)[(size_t)seg * 147456 + r] = o;
    else         ((ushort4*)wob)[r] = o;
}

// Wr rows appended at wqkv [2304, 3072)
__global__ void wr_prep(const float* __restrict__ wq,
                        const float* __restrict__ qtx, const float* __restrict__ qty,
                        ushort* __restrict__ wqkv) {
    int i = blockIdx.x * 256 + threadIdx.x;          // 768*768
    if (i >= 768 * 768) return;
    int row2 = i / 768, c = i - row2 * 768;
    ushort* dst = wqkv + (size_t)(2304 + row2) * EMB + c;
    if (row2 >= 672) { *dst = 0; return; }
    int h = row2 / 56, j = row2 - h * 56;
    const int off = (j < 28) ? 0 : 32;
    const float* tab = (j < 28) ? (qtx + j * 32) : (qty + (j - 28) * 32);
    float acc = 0.f;
#pragma unroll
    for (int d = 0; d < 32; d++)
        acc += wq[(size_t)(h * 64 + off + d) * EMB + c] * tab[d];
    *dst = f2bf(acc);
}

__global__ void rbias_k(const float* __restrict__ bq,
                        const float* __restrict__ qtx, const float* __restrict__ qty,
                        float* __restrict__ rb) {
    int i = blockIdx.x * 256 + threadIdx.x;
    if (i >= 672) return;
    int h = i / 56, j = i - h * 56;
    const int off = (j < 28) ? 0 : 32;
    const float* tab = (j < 28) ? (qtx + j * 32) : (qty + (j - 28) * 32);
    float acc = 0.f;
#pragma unroll
    for (int d = 0; d < 32; d++)
        acc += bq[h * 64 + off + d] * tab[d];
    rb[i] = acc;
}

__global__ void pack_dist(const int* __restrict__ xd, const int* __restrict__ yd,
                          int* __restrict__ xy, int n) {
    int i = blockIdx.x * 256 + threadIdx.x;
    if (i < n) xy[i] = (xd[i] & 0xffff) | (yd[i] << 16);
}

// ---------------------------------------------------------------------------
// bf16 MFMA GEMM (m97 pattern) — unchanged from r10.
// ---------------------------------------------------------------------------
template<int MODE>
__global__ __launch_bounds__(256, 2) void mfma_gemm(
    const ushort* __restrict__ A, const ushort* __restrict__ W,
    const float* __restrict__ b0, const float* __restrict__ b1, const float* __restrict__ b2,
    const float* __restrict__ rbias,
    ushort* __restrict__ q_o, ushort* __restrict__ k_o, ushort* __restrict__ v_o,
    ushort* __restrict__ r_o, float* __restrict__ f_o, int M)
{
    __shared__ __align__(16) ushort As[128 * 32];
    __shared__ __align__(16) ushort Bs[128 * 32];

    const int tid  = threadIdx.x;
    const int w    = tid >> 6, lane = tid & 63;
    const int wr   = w >> 1,  wc   = w & 1;
    const int m0   = blockIdx.x * 128;
    const int n0   = blockIdx.y * 128;
    const int srow = tid >> 2;
    const int skb  = (tid & 3) * 8;

    f32x4 acc[4][4];
#pragma unroll
    for (int m = 0; m < 4; m++)
#pragma unroll
        for (int n = 0; n < 4; n++) acc[m][n] = (f32x4)0.f;

    int ra0 = m0 + srow;       if (ra0 >= M) ra0 = M - 1;
    int ra1 = m0 + 64 + srow;  if (ra1 >= M) ra1 = M - 1;
    const int rb0 = n0 + srow, rb1 = n0 + 64 + srow;

    for (int k0 = 0; k0 < EMB; k0 += 32) {
        gl_lds16(A + (size_t)ra0 * EMB + k0 + skb, As + (w * 512));
        gl_lds16(A + (size_t)ra1 * EMB + k0 + skb, As + (2048 + w * 512));
        gl_lds16(W + (size_t)rb0 * EMB + k0 + skb, Bs + (w * 512));
        gl_lds16(W + (size_t)rb1 * EMB + k0 + skb, Bs + (2048 + w * 512));
        __syncthreads();

        bf16x8 af[4], bfr[4];
#pragma unroll
        for (int m = 0; m < 4; m++)
            af[m] = *(const bf16x8*)&As[(wr * 64 + m * 16 + (lane & 15)) * 32 + (lane >> 4) * 8];
#pragma unroll
        for (int n = 0; n < 4; n++)
            bfr[n] = *(const bf16x8*)&Bs[(wc * 64 + n * 16 + (lane & 15)) * 32 + (lane >> 4) * 8];
#pragma unroll
        for (int m = 0; m < 4; m++)
#pragma unroll
            for (int n = 0; n < 4; n++)
                acc[m][n] = __builtin_amdgcn_mfma_f32_16x16x32_bf16(af[m], bfr[n], acc[m][n], 0, 0, 0);
        __syncthreads();
    }

    const int mat = n0 / EMB;                // 0,1,2 = q,k,v ; 3 = rel region
    const int nr  = n0 % EMB;
    const float* bias = (mat == 0) ? b0 : (mat == 1) ? b1 : b2;
    ushort* dst = (mat == 0) ? q_o : (mat == 1) ? k_o : v_o;

#pragma unroll
    for (int m = 0; m < 4; m++) {
#pragma unroll
        for (int r = 0; r < 4; r++) {
            const int gm = m0 + wr * 64 + m * 16 + (lane >> 4) * 4 + r;
            if (gm >= M) continue;
            const int bb = gm / SEQ, ss = gm - bb * SEQ;
#pragma unroll
            for (int n = 0; n < 4; n++) {
                const int cl = wc * 64 + n * 16 + (lane & 15);
                if (MODE == 0) {
                    if (mat < 3) {
                        const int col = nr + cl;
                        const float v = acc[m][n][r] + bias[col];
                        dst[(((size_t)bb * NH + (col >> 6)) * SEQ + ss) * HD + (col & 63)] = f2bf(v);
                    } else {
                        const int col2 = (n0 - 2304) + cl;
                        if (col2 < 672) {
                            const int h2 = col2 / 56, j = col2 - h2 * 56;
                            const float v = acc[m][n][r] + rbias[col2];
                            r_o[((size_t)(bb * NH + h2) * SEQ + ss) * 56 + j] = f2bf(v);
                        }
                    }
                } else {
                    const int col = nr + cl;
                    f_o[(size_t)gm * EMB + col] = acc[m][n][r] + bias[col];
                }
            }
        }
    }
}

// ---------------------------------------------------------------------------
// MFMA fused attention, round 11.
//  - single-pass softmax: softmax(z) = exp(z-8)/sum(exp(z-8)) — the constant
//    cancels under normalization (exact); logits bounded |l|<~8 so no overflow.
//    acc[kt] consumed immediately -> tiny live set (448-thr budget is only
//    ~88 VGPR; r10's acc[13]-across-3-passes serialized all gathers).
//  - v_pos via MFMA: h rows (f32 LDS) -> bf16 A-frags, vtabT[64][68] B-frags.
//  - conflict fixes: P stride 232, VT transpose writes k-contiguous per 16
//    lanes, h/vtabT stride 68.
// LDS 147456 B -> 1 block/CU, 7 waves. No sync in main loop.
// ---------------------------------------------------------------------------
__global__ __launch_bounds__(NT) void attn_mfma(
    const ushort* __restrict__ xq, const ushort* __restrict__ xk, const ushort* __restrict__ xv,
    const ushort* __restrict__ rxy_g,
    const float* __restrict__ v_tab_x, const float* __restrict__ v_tab_y,
    const int* __restrict__ xy_dist,
    ushort* __restrict__ ao)
{
    __shared__ __align__(16) ushort K_s[SK * HD];        // 26624 B
    __shared__ __align__(16) ushort VT_s[HD * VP];       // 29696 B
    __shared__ __align__(16) ushort P_s[NW * 16 * PP];   // 51968 B
    __shared__ __align__(16) ushort vt_s[HD * TP];       // 8704 B
    __shared__ __align__(16) float  h_s[NW][16][HP];     // 30464 B -> 147456

    const int bh = blockIdx.x;
    const int b  = bh / NH;
    const int h  = bh % NH;
    const size_t base = (size_t)bh * SEQ * HD;
    const ushort* __restrict__ rxy_b = rxy_g + (size_t)bh * SEQ * 56;
    const int tid = threadIdx.x;
    const int w = tid >> 6, lane = tid & 63;
    const int g = lane >> 4, c15 = lane & 15;

    // ---- stage K (bf16, swizzled 16B chunks; pad rows zero) ----
    for (int idx = tid; idx < SK * 8; idx += NT) {
        const int r = idx >> 3, c = idx & 7;
        uint4 v = make_uint4(0, 0, 0, 0);
        if (r < SEQ) v = *(const uint4*)(xk + base + r * HD + c * 8);
        *(uint4*)&K_s[r * HD + ((c ^ (r & 7)) << 3)] = v;
    }
    // ---- VT pad columns zero (k in [197,232)) ----
    for (int idx = tid; idx < HD * (VP - SEQ); idx += NT) {
        const int d = idx / (VP - SEQ), k = SEQ + idx - d * (VP - SEQ);
        VT_s[d * VP + k] = 0;
    }
    // ---- P zero all ----
    for (int idx = tid; idx < NW * 16 * PP / 8; idx += NT)
        *(uint4*)&P_s[idx * 8] = make_uint4(0, 0, 0, 0);
    // ---- VT transpose write, 16 consecutive lanes -> 16 consecutive k ----
    for (int idx = tid; idx < 16 * 8 * 13; idx += NT) {
        const int kq = idx & 15, t = idx >> 4;
        const int db = t & 7, kh = t >> 3;
        const int k = kh * 16 + kq;
        if (k >= SEQ) continue;
        uint4 v = *(const uint4*)(xv + base + k * HD + db * 8);
        ushort* col = &VT_s[(db * 8) * VP + k];
        col[0 * VP] = (ushort)(v.x); col[1 * VP] = (ushort)(v.x >> 16);
        col[2 * VP] = (ushort)(v.y); col[3 * VP] = (ushort)(v.y >> 16);
        col[4 * VP] = (ushort)(v.z); col[5 * VP] = (ushort)(v.z >> 16);
        col[6 * VP] = (ushort)(v.w); col[7 * VP] = (ushort)(v.w >> 16);
    }
    // ---- vtabT[d][e] staging (constant table, bf16) ----
    for (int idx = tid; idx < HD * 64; idx += NT) {
        const int d = idx >> 6, e = idx & 63;
        float v = 0.f;
        if (d < 32) { if (e < 28) v = v_tab_x[e * 32 + d]; }
        else        { if (e >= 28 && e < 56) v = v_tab_y[(e - 28) * 32 + (d - 32)]; }
        vt_s[d * TP + e] = f2bf(v);
    }
    __syncthreads();

    // ---- main loop: wave w owns q-tiles {w, w+7} ----
    for (int qt = w; qt < 13; qt += NW) {
        const int qrow = qt * 16 + c15;
        const int qld  = (qrow < SEQ) ? qrow : (SEQ - 1);
        const bf16x8 qa0 = *(const bf16x8*)(xq + base + (size_t)qld * HD + g * 8);
        const bf16x8 qa1 = *(const bf16x8*)(xq + base + (size_t)qld * HD + 32 + g * 8);

        // zero this wave's histogram
        {
            float* hw = (float*)h_s[w];
            for (int i = lane; i < 16 * HP; i += 64) hw[i] = 0.f;
        }

        const int q4 = qt * 16 + 4 * g;   // first of this lane's 4 q rows
        float sum[4] = {0.f, 0.f, 0.f, 0.f};

        // fused QK^T -> exp -> P write -> histogram, one k-tile at a time
#pragma unroll
        for (int kt = 0; kt < 13; kt++) {
            const int kr = kt * 16 + c15;
            const int kc = (kr < SEQ) ? kr : (SEQ - 1);
            bf16x8 kf0 = *(const bf16x8*)&K_s[kr * HD + (((0 + g) ^ (kr & 7)) << 3)];
            bf16x8 kf1 = *(const bf16x8*)&K_s[kr * HD + (((4 + g) ^ (kr & 7)) << 3)];
            f32x4 a = (f32x4)0.f;
            a = __builtin_amdgcn_mfma_f32_16x16x32_bf16(qa0, kf0, a, 0, 0, 0);
            a = __builtin_amdgcn_mfma_f32_16x16x32_bf16(qa1, kf1, a, 0, 0, 0);
#pragma unroll
            for (int r = 0; r < 4; r++) {
                const int q  = q4 + r;
                const int qg = (q < SEQ) ? q : (SEQ - 1);
                const int xy = xy_dist[qg * SEQ + kc];
                const float rel = bfl(rxy_b[qg * 56 + (xy & 0xffff)])
                                + bfl(rxy_b[qg * 56 + NE + (xy >> 16)]);
                float l = (a[r] + rel) * 0.125f - 8.0f;
                if (kr >= SEQ) l = -3e38f;
                const float p = __expf(l);
                sum[r] += p;
                P_s[(w * 16 + 4 * g + r) * PP + kr] = f2bf(p);
                atomicAdd(&h_s[w][4 * g + r][xy & 0xffff], p);
                atomicAdd(&h_s[w][4 * g + r][NE + (xy >> 16)], p);
            }
        }
        float inv[4];
#pragma unroll
        for (int r = 0; r < 4; r++) {
            sum[r] += __shfl_xor(sum[r], 1);
            sum[r] += __shfl_xor(sum[r], 2);
            sum[r] += __shfl_xor(sum[r], 4);
            sum[r] += __shfl_xor(sum[r], 8);
            inv[r] = 1.f / sum[r];
        }

        // PV (unnormalized): O[q][d] = sum_k P[q][k] * VT[d][k]
        f32x4 o[4];
#pragma unroll
        for (int dt = 0; dt < 4; dt++) o[dt] = (f32x4)0.f;
#pragma unroll
        for (int ks = 0; ks < 7; ks++) {
            bf16x8 pf = *(const bf16x8*)&P_s[(w * 16 + c15) * PP + ks * 32 + g * 8];
#pragma unroll
            for (int dt = 0; dt < 4; dt++) {
                bf16x8 vf = *(const bf16x8*)&VT_s[(dt * 16 + c15) * VP + ks * 32 + g * 8];
                o[dt] = __builtin_amdgcn_mfma_f32_16x16x32_bf16(pf, vf, o[dt], 0, 0, 0);
            }
        }

        // v_pos via MFMA: O += H[q][e] x vtabT[d][e]  (e padded to 64)
#pragma unroll
        for (int ks2 = 0; ks2 < 2; ks2++) {
            float4 ha = *(const float4*)&h_s[w][c15][ks2 * 32 + g * 8];
            float4 hb = *(const float4*)&h_s[w][c15][ks2 * 32 + g * 8 + 4];
            uint4 up;
            up.x = (unsigned)f2bf(ha.x) | ((unsigned)f2bf(ha.y) << 16);
            up.y = (unsigned)f2bf(ha.z) | ((unsigned)f2bf(ha.w) << 16);
            up.z = (unsigned)f2bf(hb.x) | ((unsigned)f2bf(hb.y) << 16);
            up.w = (unsigned)f2bf(hb.z) | ((unsigned)f2bf(hb.w) << 16);
            bf16x8 hf = *(bf16x8*)&up;
#pragma unroll
            for (int dt = 0; dt < 4; dt++) {
                bf16x8 tf = *(const bf16x8*)&vt_s[(dt * 16 + c15) * TP + ks2 * 32 + g * 8];
                o[dt] = __builtin_amdgcn_mfma_f32_16x16x32_bf16(hf, tf, o[dt], 0, 0, 0);
            }
        }

        // store (normalize here; exp offset cancels)
#pragma unroll
        for (int dt = 0; dt < 4; dt++) {
            const int d = dt * 16 + c15;
#pragma unroll
            for (int r = 0; r < 4; r++) {
                const int q = q4 + r;
                if (q < SEQ)
                    ao[((size_t)(b * SEQ + q)) * EMB + h * HD + d] = f2bf(o[dt][r] * inv[r]);
            }
        }
    }
}

extern "C" void kernel_launch(void* const* d_in, const int* in_sizes, int n_in,
                              void* d_out, int out_size, void* d_ws, size_t ws_size,
                              hipStream_t stream) {
    const float* x       = (const float*)d_in[0];
    const float* Wq      = (const float*)d_in[1];
    const float* bq      = (const float*)d_in[2];
    const float* Wk      = (const float*)d_in[3];
    const float* bk      = (const float*)d_in[4];
    const float* Wv      = (const float*)d_in[5];
    const float* bv      = (const float*)d_in[6];
    const float* Wo      = (const float*)d_in[7];
    const float* bo      = (const float*)d_in[8];
    const float* q_tab_x = (const float*)d_in[9];
    const float* q_tab_y = (const float*)d_in[10];
    const float* v_tab_x = (const float*)d_in[11];
    const float* v_tab_y = (const float*)d_in[12];
    const int*   x_dist  = (const int*)d_in[13];
    const int*   y_dist  = (const int*)d_in[14];
    float* out = (float*)d_out;

    const int M  = in_sizes[0] / EMB;   // 12608
    const int Bc = M / SEQ;             // 64

    // ws carve (bf16 = ushort)
    ushort* xb   = (ushort*)d_ws;                       // M*768
    ushort* wqkv = xb   + (size_t)M * EMB;              // 3072*768 (q|k|v|Wr)
    ushort* wob  = wqkv + (size_t)3072 * EMB;           // 768*768
    ushort* xqb  = wob  + (size_t)EMB * EMB;            // M*768
    ushort* xkb  = xqb  + (size_t)M * EMB;
    ushort* xvb  = xkb  + (size_t)M * EMB;
    ushort* aob  = xvb  + (size_t)M * EMB;
    ushort* r_o  = aob  + (size_t)M * EMB;              // 768*197*56
    float*  rbia = (float*)(r_o + (size_t)Bc * NH * SEQ * 56);
    int*    xyd  = (int*)(rbia + 672);

    const int n4x = M * EMB / 4;
    cvt_k<<<dim3((n4x + 255) / 256), dim3(256), 0, stream>>>(x, xb, n4x);
    cvt_w4<<<dim3(2304), dim3(256), 0, stream>>>(Wq, Wk, Wv, Wo, wqkv, wob);
    wr_prep<<<dim3(2304), dim3(256), 0, stream>>>(Wq, q_tab_x, q_tab_y, wqkv);
    rbias_k<<<dim3(3), dim3(256), 0, stream>>>(bq, q_tab_x, q_tab_y, rbia);
    pack_dist<<<dim3((SEQ * SEQ + 255) / 256), dim3(256), 0, stream>>>(
        x_dist, y_dist, xyd, SEQ * SEQ);

    mfma_gemm<0><<<dim3((M + 127) / 128, 24), dim3(256), 0, stream>>>(
        xb, wqkv, bq, bk, bv, rbia, xqb, xkb, xvb, r_o, nullptr, M);

    attn_mfma<<<dim3(Bc * NH), dim3(NT), 0, stream>>>(
        xqb, xkb, xvb, r_o, v_tab_x, v_tab_y, xyd, aob);

    mfma_gemm<1><<<dim3((M + 127) / 128, 6), dim3(256), 0, stream>>>(
        aob, wob, bo, bo, bo, nullptr, nullptr, nullptr, nullptr, nullptr, out, M);
}

// Round 12
// 225.908 us; speedup vs baseline: 5.7495x; 2.6141x over previous
//
#include <hip/hip_runtime.h>
#include <math.h>

#define SEQ 197
#define EMB 768
#define NH  12
#define HD  64
#define NE  28
#define SK  208   // padded K rows (13 tiles of 16)
#define VP  232   // VT row length (k)
#define PP  232   // P row length (k)
#define EP  232   // EXYT row length (k)
#define HP  68    // h row length (bf16)
#define TP  66    // vtabT row length
#define NW  7     // waves per attn block
#define NT  448   // attn threads

typedef __attribute__((ext_vector_type(8))) __bf16 bf16x8;
typedef __attribute__((ext_vector_type(4))) float  f32x4;

__device__ __forceinline__ unsigned short f2bf(float f) {
    unsigned u = __float_as_uint(f);
    u += 0x7fffu + ((u >> 16) & 1u);
    return (unsigned short)(u >> 16);
}
__device__ __forceinline__ float bfl(unsigned u) { return __uint_as_float(u << 16); }

__device__ __forceinline__ void gl_lds16(const ushort* g, ushort* l) {
    __builtin_amdgcn_global_load_lds(
        (const __attribute__((address_space(1))) unsigned int*)g,
        (__attribute__((address_space(3))) unsigned int*)l, 16, 0, 0);
}

// ---------------------------------------------------------------------------
// prep kernels
// ---------------------------------------------------------------------------
__global__ void cvt_k(const float* __restrict__ src, ushort* __restrict__ dst, int n4) {
    int i = blockIdx.x * 256 + threadIdx.x;
    if (i < n4) {
        float4 v = ((const float4*)src)[i];
        ushort4 o = { f2bf(v.x), f2bf(v.y), f2bf(v.z), f2bf(v.w) };
        ((ushort4*)dst)[i] = o;
    }
}

__global__ void cvt_w4(const float* __restrict__ wq, const float* __restrict__ wk,
                       const float* __restrict__ wv, const float* __restrict__ wo,
                       ushort* __restrict__ wqkv, ushort* __restrict__ wob) {
    int i = blockIdx.x * 256 + threadIdx.x;          // 4 * 147456 total
    if (i >= 4 * 147456) return;
    int seg = i / 147456, r = i - seg * 147456;
    const float* s = (seg == 0) ? wq : (seg == 1) ? wk : (seg == 2) ? wv : wo;
    float4 v = ((const float4*)s)[r];
    ushort4 o = { f2bf(v.x), f2bf(v.y), f2bf(v.z), f2bf(v.w) };
    if (seg < 3) ((ushort4*)wqkv)[(size_t)seg * 147456 + r] = o;
    else         ((ushort4*)wob)[r] = o;
}

// Wr rows appended at wqkv [2304, 3072)
__global__ void wr_prep(const float* __restrict__ wq,
                        const float* __restrict__ qtx, const float* __restrict__ qty,
                        ushort* __restrict__ wqkv) {
    int i = blockIdx.x * 256 + threadIdx.x;          // 768*768
    if (i >= 768 * 768) return;
    int row2 = i / 768, c = i - row2 * 768;
    ushort* dst = wqkv + (size_t)(2304 + row2) * EMB + c;
    if (row2 >= 672) { *dst = 0; return; }
    int h = row2 / 56, j = row2 - h * 56;
    const int off = (j < 28) ? 0 : 32;
    const float* tab = (j < 28) ? (qtx + j * 32) : (qty + (j - 28) * 32);
    float acc = 0.f;
#pragma unroll
    for (int d = 0; d < 32; d++)
        acc += wq[(size_t)(h * 64 + off + d) * EMB + c] * tab[d];
    *dst = f2bf(acc);
}

__global__ void rbias_k(const float* __restrict__ bq,
                        const float* __restrict__ qtx, const float* __restrict__ qty,
                        float* __restrict__ rb) {
    int i = blockIdx.x * 256 + threadIdx.x;
    if (i >= 672) return;
    int h = i / 56, j = i - h * 56;
    const int off = (j < 28) ? 0 : 32;
    const float* tab = (j < 28) ? (qtx + j * 32) : (qty + (j - 28) * 32);
    float acc = 0.f;
#pragma unroll
    for (int d = 0; d < 32; d++)
        acc += bq[h * 64 + off + d] * tab[d];
    rb[i] = acc;
}

// ---------------------------------------------------------------------------
// bf16 MFMA GEMM (m97 pattern) — unchanged.
// ---------------------------------------------------------------------------
template<int MODE>
__global__ __launch_bounds__(256, 2) void mfma_gemm(
    const ushort* __restrict__ A, const ushort* __restrict__ W,
    const float* __restrict__ b0, const float* __restrict__ b1, const float* __restrict__ b2,
    const float* __restrict__ rbias,
    ushort* __restrict__ q_o, ushort* __restrict__ k_o, ushort* __restrict__ v_o,
    ushort* __restrict__ r_o, float* __restrict__ f_o, int M)
{
    __shared__ __align__(16) ushort As[128 * 32];
    __shared__ __align__(16) ushort Bs[128 * 32];

    const int tid  = threadIdx.x;
    const int w    = tid >> 6, lane = tid & 63;
    const int wr   = w >> 1,  wc   = w & 1;
    const int m0   = blockIdx.x * 128;
    const int n0   = blockIdx.y * 128;
    const int srow = tid >> 2;
    const int skb  = (tid & 3) * 8;

    f32x4 acc[4][4];
#pragma unroll
    for (int m = 0; m < 4; m++)
#pragma unroll
        for (int n = 0; n < 4; n++) acc[m][n] = (f32x4)0.f;

    int ra0 = m0 + srow;       if (ra0 >= M) ra0 = M - 1;
    int ra1 = m0 + 64 + srow;  if (ra1 >= M) ra1 = M - 1;
    const int rb0 = n0 + srow, rb1 = n0 + 64 + srow;

    for (int k0 = 0; k0 < EMB; k0 += 32) {
        gl_lds16(A + (size_t)ra0 * EMB + k0 + skb, As + (w * 512));
        gl_lds16(A + (size_t)ra1 * EMB + k0 + skb, As + (2048 + w * 512));
        gl_lds16(W + (size_t)rb0 * EMB + k0 + skb, Bs + (w * 512));
        gl_lds16(W + (size_t)rb1 * EMB + k0 + skb, Bs + (2048 + w * 512));
        __syncthreads();

        bf16x8 af[4], bfr[4];
#pragma unroll
        for (int m = 0; m < 4; m++)
            af[m] = *(const bf16x8*)&As[(wr * 64 + m * 16 + (lane & 15)) * 32 + (lane >> 4) * 8];
#pragma unroll
        for (int n = 0; n < 4; n++)
            bfr[n] = *(const bf16x8*)&Bs[(wc * 64 + n * 16 + (lane & 15)) * 32 + (lane >> 4) * 8];
#pragma unroll
        for (int m = 0; m < 4; m++)
#pragma unroll
            for (int n = 0; n < 4; n++)
                acc[m][n] = __builtin_amdgcn_mfma_f32_16x16x32_bf16(af[m], bfr[n], acc[m][n], 0, 0, 0);
        __syncthreads();
    }

    const int mat = n0 / EMB;                // 0,1,2 = q,k,v ; 3 = rel region
    const int nr  = n0 % EMB;
    const float* bias = (mat == 0) ? b0 : (mat == 1) ? b1 : b2;
    ushort* dst = (mat == 0) ? q_o : (mat == 1) ? k_o : v_o;

#pragma unroll
    for (int m = 0; m < 4; m++) {
#pragma unroll
        for (int r = 0; r < 4; r++) {
            const int gm = m0 + wr * 64 + m * 16 + (lane >> 4) * 4 + r;
            if (gm >= M) continue;
            const int bb = gm / SEQ, ss = gm - bb * SEQ;
#pragma unroll
            for (int n = 0; n < 4; n++) {
                const int cl = wc * 64 + n * 16 + (lane & 15);
                if (MODE == 0) {
                    if (mat < 3) {
                        const int col = nr + cl;
                        const float v = acc[m][n][r] + bias[col];
                        dst[(((size_t)bb * NH + (col >> 6)) * SEQ + ss) * HD + (col & 63)] = f2bf(v);
                    } else {
                        const int col2 = (n0 - 2304) + cl;
                        if (col2 < 672) {
                            const int h2 = col2 / 56, j = col2 - h2 * 56;
                            const float v = acc[m][n][r] + rbias[col2];
                            r_o[((size_t)(bb * NH + h2) * SEQ + ss) * 56 + j] = f2bf(v);
                        }
                    }
                } else {
                    const int col = nr + cl;
                    f_o[(size_t)gm * EMB + col] = acc[m][n][r] + bias[col];
                }
            }
        }
    }
}

// ---------------------------------------------------------------------------
// MFMA fused attention, round 12 — one-hot factorization.
// Distances are never clipped (|dx|,|dy|<=13), so xd[q,k]=cx[k]-cx[q]+14 with
// cx[k]=x_dist[1*SEQ+k]-14. Augmented QK^T (96-dim: 64 Q + 16 x-onehot +
// 16 y-onehot) computes content+rel logits entirely in MFMA. Histogram via
// PXY = P x EXY MFMA + injective per-q index shift (plain bf16 stores, no
// atomics; q=0 CLS row via 16-lane butterfly). v_pos MFMA reads h directly.
// Hot loop: 3 ds_read + 3 MFMA + 4 exp + 4 ds_write. No global, no atomics.
// LDS 163456 B -> 1 block/CU, 7 waves.
// ---------------------------------------------------------------------------
__global__ __launch_bounds__(NT) void attn_mfma(
    const ushort* __restrict__ xq, const ushort* __restrict__ xk, const ushort* __restrict__ xv,
    const ushort* __restrict__ rxy_g,
    const float* __restrict__ v_tab_x, const float* __restrict__ v_tab_y,
    const int* __restrict__ x_dist, const int* __restrict__ y_dist,
    ushort* __restrict__ ao)
{
    __shared__ __align__(16) ushort K_s[SK * HD];        // 26624 B
    __shared__ __align__(16) ushort EXYs_s[SK * 40];     // 16640 B  [k][c]
    __shared__ __align__(16) ushort EXYT_s[32 * EP];     // 14848 B  [c][k]
    __shared__ __align__(16) ushort VT_s[HD * VP];       // 29696 B
    __shared__ __align__(16) ushort P_s[NW * 16 * PP];   // 51968 B
    __shared__ __align__(16) ushort vt_s[HD * TP];       // 8448 B
    __shared__ __align__(16) ushort h_s[NW][16][HP];     // 15232 B -> 163456

    const int bh = blockIdx.x;
    const int b  = bh / NH;
    const int h  = bh % NH;
    const size_t base = (size_t)bh * SEQ * HD;
    const ushort* __restrict__ rxy_b = rxy_g + (size_t)bh * SEQ * 56;
    const int tid = threadIdx.x;
    const int w = tid >> 6, lane = tid & 63;
    const int g = lane >> 4, c15 = lane & 15;

    // ---- stage K (bf16, swizzled 16B chunks; pad rows zero) ----
    for (int idx = tid; idx < SK * 8; idx += NT) {
        const int r = idx >> 3, c = idx & 7;
        uint4 v = make_uint4(0, 0, 0, 0);
        if (r < SEQ) v = *(const uint4*)(xk + base + r * HD + c * 8);
        *(uint4*)&K_s[r * HD + ((c ^ (r & 7)) << 3)] = v;
    }
    // ---- zero EXYs / EXYT ----
    for (int idx = tid; idx < SK * 40 / 8; idx += NT)
        *(uint4*)&EXYs_s[idx * 8] = make_uint4(0, 0, 0, 0);
    for (int idx = tid; idx < 32 * EP / 8; idx += NT)
        *(uint4*)&EXYT_s[idx * 8] = make_uint4(0, 0, 0, 0);
    // ---- VT pad columns zero ----
    for (int idx = tid; idx < HD * (VP - SEQ); idx += NT) {
        const int d = idx / (VP - SEQ), k = SEQ + idx - d * (VP - SEQ);
        VT_s[d * VP + k] = 0;
    }
    // ---- P zero all (pad cols [208,224) must be 0) ----
    for (int idx = tid; idx < NW * 16 * PP / 8; idx += NT)
        *(uint4*)&P_s[idx * 8] = make_uint4(0, 0, 0, 0);
    // ---- VT transpose write, 16 consecutive lanes -> 16 consecutive k ----
    for (int idx = tid; idx < 16 * 8 * 13; idx += NT) {
        const int kq = idx & 15, t = idx >> 4;
        const int db = t & 7, kh = t >> 3;
        const int k = kh * 16 + kq;
        if (k >= SEQ) continue;
        uint4 v = *(const uint4*)(xv + base + k * HD + db * 8);
        ushort* col = &VT_s[(db * 8) * VP + k];
        col[0 * VP] = (ushort)(v.x); col[1 * VP] = (ushort)(v.x >> 16);
        col[2 * VP] = (ushort)(v.y); col[3 * VP] = (ushort)(v.y >> 16);
        col[4 * VP] = (ushort)(v.z); col[5 * VP] = (ushort)(v.z >> 16);
        col[6 * VP] = (ushort)(v.w); col[7 * VP] = (ushort)(v.w >> 16);
    }
    // ---- vtabT[d][e] staging ----
    for (int idx = tid; idx < HD * 64; idx += NT) {
        const int d = idx >> 6, e = idx & 63;
        float v = 0.f;
        if (d < 32) { if (e < 28) v = v_tab_x[e * 32 + d]; }
        else        { if (e >= 28 && e < 56) v = v_tab_y[(e - 28) * 32 + (d - 32)]; }
        vt_s[d * TP + e] = f2bf(v);
    }
    __syncthreads();   // zero EXY visible before one-hot fill (cross-wave)
    // ---- one-hot fill (cx from x_dist row 1; CLS -> flag col 14 / 30) ----
    for (int k = tid; k < SEQ; k += NT) {
        const int cx = (k == 0) ? 14 : (x_dist[SEQ + k] - 14);
        const int cy = (k == 0) ? 14 : (y_dist[SEQ + k] - 14);
        const ushort one = 0x3f80;   // bf16 1.0
        EXYs_s[k * 40 + cx]        = one;
        EXYs_s[k * 40 + 16 + cy]   = one;
        EXYT_s[cx * EP + k]        = one;
        EXYT_s[(16 + cy) * EP + k] = one;
    }
    __syncthreads();

    // ---- main loop: wave w owns q-tiles {w, w+7} ----
    for (int qt = w; qt < 13; qt += NW) {
        const int qrow = qt * 16 + c15;
        const int qld  = (qrow < SEQ) ? qrow : (SEQ - 1);
        const bf16x8 qa0 = *(const bf16x8*)(xq + base + (size_t)qld * HD + g * 8);
        const bf16x8 qa1 = *(const bf16x8*)(xq + base + (size_t)qld * HD + 32 + g * 8);

        // build augmented Q frag (dims 64..95): Raug[q][c], c = g*8..g*8+7
        uint4 up;
        {
            const ushort* rrow = rxy_b + qld * 56;
            const int cxq = (qld > 0) ? (x_dist[SEQ + qld] - 14) : 0;
            const int cyq = (qld > 0) ? (y_dist[SEQ + qld] - 14) : 0;
            unsigned uu[4] = {0, 0, 0, 0};
#pragma unroll
            for (int j = 0; j < 8; j++) {
                const int c = g * 8 + j;
                ushort v;
                if (qld == 0)      v = (c == 15 || c == 31) ? (ushort)0 : rrow[(c < 16) ? 0 : 28];
                else if (c < 14)   v = rrow[c - cxq + 14];
                else if (c == 14)  v = rrow[0];
                else if (c == 15)  v = 0;
                else if (c < 30)   v = rrow[28 + (c - 16) - cyq + 14];
                else if (c == 30)  v = rrow[28];
                else               v = 0;
                uu[j >> 1] |= ((unsigned)v) << ((j & 1) * 16);
            }
            up.x = uu[0]; up.y = uu[1]; up.z = uu[2]; up.w = uu[3];
        }
        const bf16x8 qa2 = *(bf16x8*)&up;

        // zero this wave's histogram (16*HP ushorts = 136 uint4)
        {
            uint4* hz = (uint4*)h_s[w];
            for (int i = lane; i < 16 * HP / 8; i += 64) hz[i] = make_uint4(0, 0, 0, 0);
        }

        const int q4 = qt * 16 + 4 * g;
        float sum[4] = {0.f, 0.f, 0.f, 0.f};

        // fused augmented QK^T -> exp -> P write
#pragma unroll
        for (int kt = 0; kt < 13; kt++) {
            const int kr = kt * 16 + c15;
            bf16x8 kf0 = *(const bf16x8*)&K_s[kr * HD + (((0 + g) ^ (kr & 7)) << 3)];
            bf16x8 kf1 = *(const bf16x8*)&K_s[kr * HD + (((4 + g) ^ (kr & 7)) << 3)];
            bf16x8 kf2 = *(const bf16x8*)&EXYs_s[kr * 40 + g * 8];
            f32x4 a = (f32x4)0.f;
            a = __builtin_amdgcn_mfma_f32_16x16x32_bf16(qa0, kf0, a, 0, 0, 0);
            a = __builtin_amdgcn_mfma_f32_16x16x32_bf16(qa1, kf1, a, 0, 0, 0);
            a = __builtin_amdgcn_mfma_f32_16x16x32_bf16(qa2, kf2, a, 0, 0, 0);
#pragma unroll
            for (int r = 0; r < 4; r++) {
                const float l = a[r] * 0.125f - 8.0f;
                const float p = (kr < SEQ) ? __expf(l) : 0.f;
                sum[r] += p;
                P_s[(w * 16 + 4 * g + r) * PP + kr] = f2bf(p);
            }
        }
        float inv[4];
#pragma unroll
        for (int r = 0; r < 4; r++) {
            sum[r] += __shfl_xor(sum[r], 1);
            sum[r] += __shfl_xor(sum[r], 2);
            sum[r] += __shfl_xor(sum[r], 4);
            sum[r] += __shfl_xor(sum[r], 8);
            inv[r] = 1.f / sum[r];
        }

        // PXY = P x EXY (cols 0..15 = x, 16..31 = y)
        f32x4 px0 = (f32x4)0.f, px1 = (f32x4)0.f;
#pragma unroll
        for (int ks = 0; ks < 7; ks++) {
            bf16x8 pf = *(const bf16x8*)&P_s[(w * 16 + c15) * PP + ks * 32 + g * 8];
            bf16x8 e0 = *(const bf16x8*)&EXYT_s[c15 * EP + ks * 32 + g * 8];
            bf16x8 e1 = *(const bf16x8*)&EXYT_s[(16 + c15) * EP + ks * 32 + g * 8];
            px0 = __builtin_amdgcn_mfma_f32_16x16x32_bf16(pf, e0, px0, 0, 0, 0);
            px1 = __builtin_amdgcn_mfma_f32_16x16x32_bf16(pf, e1, px1, 0, 0, 0);
        }

        // q==0 CLS sums (all mass -> bin 0 / 28); only wave with qt==0 uses it
        float sx = px0[0], sy = px1[0];
        if (qt == 0) {
            sx += __shfl_xor(sx, 1); sx += __shfl_xor(sx, 2);
            sx += __shfl_xor(sx, 4); sx += __shfl_xor(sx, 8);
            sy += __shfl_xor(sy, 1); sy += __shfl_xor(sy, 2);
            sy += __shfl_xor(sy, 4); sy += __shfl_xor(sy, 8);
        }

        // histogram via injective remap (plain stores)
#pragma unroll
        for (int r = 0; r < 4; r++) {
            const int q = q4 + r;
            if (q >= SEQ) continue;
            const int ql = 4 * g + r;
            if (q == 0) {
                if (c15 == 14) { h_s[w][ql][0] = f2bf(sx); h_s[w][ql][28] = f2bf(sy); }
            } else {
                const int cxq2 = x_dist[SEQ + q] - 14;
                const int cyq2 = y_dist[SEQ + q] - 14;
                if (c15 < 14) {
                    h_s[w][ql][c15 - cxq2 + 14]        = f2bf(px0[r]);
                    h_s[w][ql][28 + c15 - cyq2 + 14]   = f2bf(px1[r]);
                } else if (c15 == 14) {
                    h_s[w][ql][0]  = f2bf(px0[r]);
                    h_s[w][ql][28] = f2bf(px1[r]);
                }
            }
        }

        // PV: O[q][d] = sum_k P[q][k] * VT[d][k]
        f32x4 o[4];
#pragma unroll
        for (int dt = 0; dt < 4; dt++) o[dt] = (f32x4)0.f;
#pragma unroll
        for (int ks = 0; ks < 7; ks++) {
            bf16x8 pf = *(const bf16x8*)&P_s[(w * 16 + c15) * PP + ks * 32 + g * 8];
#pragma unroll
            for (int dt = 0; dt < 4; dt++) {
                bf16x8 vf = *(const bf16x8*)&VT_s[(dt * 16 + c15) * VP + ks * 32 + g * 8];
                o[dt] = __builtin_amdgcn_mfma_f32_16x16x32_bf16(pf, vf, o[dt], 0, 0, 0);
            }
        }

        // v_pos via MFMA: O += H[q][e] x vtabT[d][e]
#pragma unroll
        for (int ks2 = 0; ks2 < 2; ks2++) {
            bf16x8 hf = *(const bf16x8*)&h_s[w][c15][ks2 * 32 + g * 8];
#pragma unroll
            for (int dt = 0; dt < 4; dt++) {
                bf16x8 tf = *(const bf16x8*)&vt_s[(dt * 16 + c15) * TP + ks2 * 32 + g * 8];
                o[dt] = __builtin_amdgcn_mfma_f32_16x16x32_bf16(hf, tf, o[dt], 0, 0, 0);
            }
        }

        // store (normalize; exp offset cancels)
#pragma unroll
        for (int dt = 0; dt < 4; dt++) {
            const int d = dt * 16 + c15;
#pragma unroll
            for (int r = 0; r < 4; r++) {
                const int q = q4 + r;
                if (q < SEQ)
                    ao[((size_t)(b * SEQ + q)) * EMB + h * HD + d] = f2bf(o[dt][r] * inv[r]);
            }
        }
    }
}

extern "C" void kernel_launch(void* const* d_in, const int* in_sizes, int n_in,
                              void* d_out, int out_size, void* d_ws, size_t ws_size,
                              hipStream_t stream) {
    const float* x       = (const float*)d_in[0];
    const float* Wq      = (const float*)d_in[1];
    const float* bq      = (const float*)d_in[2];
    const float* Wk      = (const float*)d_in[3];
    const float* bk      = (const float*)d_in[4];
    const float* Wv      = (const float*)d_in[5];
    const float* bv      = (const float*)d_in[6];
    const float* Wo      = (const float*)d_in[7];
    const float* bo      = (const float*)d_in[8];
    const float* q_tab_x = (const float*)d_in[9];
    const float* q_tab_y = (const float*)d_in[10];
    const float* v_tab_x = (const float*)d_in[11];
    const float* v_tab_y = (const float*)d_in[12];
    const int*   x_dist  = (const int*)d_in[13];
    const int*   y_dist  = (const int*)d_in[14];
    float* out = (float*)d_out;

    const int M  = in_sizes[0] / EMB;   // 12608
    const int Bc = M / SEQ;             // 64

    // ws carve (bf16 = ushort)
    ushort* xb   = (ushort*)d_ws;                       // M*768
    ushort* wqkv = xb   + (size_t)M * EMB;              // 3072*768 (q|k|v|Wr)
    ushort* wob  = wqkv + (size_t)3072 * EMB;           // 768*768
    ushort* xqb  = wob  + (size_t)EMB * EMB;            // M*768
    ushort* xkb  = xqb  + (size_t)M * EMB;
    ushort* xvb  = xkb  + (size_t)M * EMB;
    ushort* aob  = xvb  + (size_t)M * EMB;
    ushort* r_o  = aob  + (size_t)M * EMB;              // 768*197*56
    float*  rbia = (float*)(r_o + (size_t)Bc * NH * SEQ * 56);

    const int n4x = M * EMB / 4;
    cvt_k<<<dim3((n4x + 255) / 256), dim3(256), 0, stream>>>(x, xb, n4x);
    cvt_w4<<<dim3(2304), dim3(256), 0, stream>>>(Wq, Wk, Wv, Wo, wqkv, wob);
    wr_prep<<<dim3(2304), dim3(256), 0, stream>>>(Wq, q_tab_x, q_tab_y, wqkv);
    rbias_k<<<dim3(3), dim3(256), 0, stream>>>(bq, q_tab_x, q_tab_y, rbia);

    mfma_gemm<0><<<dim3((M + 127) / 128, 24), dim3(256), 0, stream>>>(
        xb, wqkv, bq, bk, bv, rbia, xqb, xkb, xvb, r_o, nullptr, M);

    attn_mfma<<<dim3(Bc * NH), dim3(NT), 0, stream>>>(
        xqb, xkb, xvb, r_o, v_tab_x, v_tab_y, x_dist, y_dist, aob);

    mfma_gemm<1><<<dim3((M + 127) / 128, 6), dim3(256), 0, stream>>>(
        aob, wob, bo, bo, bo, nullptr, nullptr, nullptr, nullptr, nullptr, out, M);
}

// Round 13
// 210.998 us; speedup vs baseline: 6.1558x; 1.0707x over previous
//
#include <hip/hip_runtime.h>
#include <math.h>

#define SEQ 197
#define EMB 768
#define NH  12
#define HD  64
#define NE  28
#define SK  208   // padded K rows (13 tiles of 16)
#define VP  232   // VT row length (k)
#define PP  232   // P row length (k)
#define EP  232   // EXYT row length (k)
#define HP  68    // h row length (bf16)
#define TP  66    // vtabT row length
#define NW  7     // waves per attn block
#define NT  448   // attn threads

typedef __attribute__((ext_vector_type(8))) __bf16 bf16x8;
typedef __attribute__((ext_vector_type(4))) float  f32x4;

__device__ __forceinline__ unsigned short f2bf(float f) {
    unsigned u = __float_as_uint(f);
    u += 0x7fffu + ((u >> 16) & 1u);
    return (unsigned short)(u >> 16);
}
__device__ __forceinline__ float bfl(unsigned u) { return __uint_as_float(u << 16); }

__device__ __forceinline__ void gl_lds16(const ushort* g, ushort* l) {
    __builtin_amdgcn_global_load_lds(
        (const __attribute__((address_space(1))) unsigned int*)g,
        (__attribute__((address_space(3))) unsigned int*)l, 16, 0, 0);
}

// ---------------------------------------------------------------------------
// prep kernels
// ---------------------------------------------------------------------------
__global__ void cvt_k(const float* __restrict__ src, ushort* __restrict__ dst, int n4) {
    int i = blockIdx.x * 256 + threadIdx.x;
    if (i < n4) {
        float4 v = ((const float4*)src)[i];
        ushort4 o = { f2bf(v.x), f2bf(v.y), f2bf(v.z), f2bf(v.w) };
        ((ushort4*)dst)[i] = o;
    }
}

__global__ void cvt_w4(const float* __restrict__ wq, const float* __restrict__ wk,
                       const float* __restrict__ wv, const float* __restrict__ wo,
                       ushort* __restrict__ wqkv, ushort* __restrict__ wob) {
    int i = blockIdx.x * 256 + threadIdx.x;          // 4 * 147456 total
    if (i >= 4 * 147456) return;
    int seg = i / 147456, r = i - seg * 147456;
    const float* s = (seg == 0) ? wq : (seg == 1) ? wk : (seg == 2) ? wv : wo;
    float4 v = ((const float4*)s)[r];
    ushort4 o = { f2bf(v.x), f2bf(v.y), f2bf(v.z), f2bf(v.w) };
    if (seg < 3) ((ushort4*)wqkv)[(size_t)seg * 147456 + r] = o;
    else         ((ushort4*)wob)[r] = o;
}

// Wr rows appended at wqkv [2304, 3072)
__global__ void wr_prep(const float* __restrict__ wq,
                        const float* __restrict__ qtx, const float* __restrict__ qty,
                        ushort* __restrict__ wqkv) {
    int i = blockIdx.x * 256 + threadIdx.x;          // 768*768
    if (i >= 768 * 768) return;
    int row2 = i / 768, c = i - row2 * 768;
    ushort* dst = wqkv + (size_t)(2304 + row2) * EMB + c;
    if (row2 >= 672) { *dst = 0; return; }
    int h = row2 / 56, j = row2 - h * 56;
    const int off = (j < 28) ? 0 : 32;
    const float* tab = (j < 28) ? (qtx + j * 32) : (qty + (j - 28) * 32);
    float acc = 0.f;
#pragma unroll
    for (int d = 0; d < 32; d++)
        acc += wq[(size_t)(h * 64 + off + d) * EMB + c] * tab[d];
    *dst = f2bf(acc);
}

__global__ void rbias_k(const float* __restrict__ bq,
                        const float* __restrict__ qtx, const float* __restrict__ qty,
                        float* __restrict__ rb) {
    int i = blockIdx.x * 256 + threadIdx.x;
    if (i >= 672) return;
    int h = i / 56, j = i - h * 56;
    const int off = (j < 28) ? 0 : 32;
    const float* tab = (j < 28) ? (qtx + j * 32) : (qty + (j - 28) * 32);
    float acc = 0.f;
#pragma unroll
    for (int d = 0; d < 32; d++)
        acc += bq[h * 64 + off + d] * tab[d];
    rb[i] = acc;
}

// ---------------------------------------------------------------------------
// bf16 MFMA GEMM (m97 pattern) + XCD-chunked grid swizzle (r13):
// 8 consecutive-dispatch blocks (~one per XCD) share nt and span 8 mts, so
// each XCD sweeps all nt with its own A-panel L2-resident (was: A streamed
// from HBM ~12x -> 250 MB FETCH/dispatch).
// ---------------------------------------------------------------------------
template<int MODE>
__global__ __launch_bounds__(256, 2) void mfma_gemm(
    const ushort* __restrict__ A, const ushort* __restrict__ W,
    const float* __restrict__ b0, const float* __restrict__ b1, const float* __restrict__ b2,
    const float* __restrict__ rbias,
    ushort* __restrict__ q_o, ushort* __restrict__ k_o, ushort* __restrict__ v_o,
    ushort* __restrict__ r_o, float* __restrict__ f_o, int M)
{
    __shared__ __align__(16) ushort As[128 * 32];
    __shared__ __align__(16) ushort Bs[128 * 32];

    const int tid  = threadIdx.x;
    const int w    = tid >> 6, lane = tid & 63;
    const int wr   = w >> 1,  wc   = w & 1;

    // ---- XCD-chunked swizzle (bijective incl. tail group) ----
    const int nmt = gridDim.x, nnt = gridDim.y;
    const int l   = blockIdx.y * nmt + blockIdx.x;
    const int gsz = 8 * nnt;
    const int grp = l / gsz;
    const int rr  = l - grp * gsz;
    int mig = nmt - grp * 8; if (mig > 8) mig = 8;
    const int mt  = grp * 8 + rr % mig;
    const int nt  = rr / mig;
    const int m0  = mt * 128;
    const int n0  = nt * 128;

    const int srow = tid >> 2;
    const int skb  = (tid & 3) * 8;

    f32x4 acc[4][4];
#pragma unroll
    for (int m = 0; m < 4; m++)
#pragma unroll
        for (int n = 0; n < 4; n++) acc[m][n] = (f32x4)0.f;

    int ra0 = m0 + srow;       if (ra0 >= M) ra0 = M - 1;
    int ra1 = m0 + 64 + srow;  if (ra1 >= M) ra1 = M - 1;
    const int rb0 = n0 + srow, rb1 = n0 + 64 + srow;

    for (int k0 = 0; k0 < EMB; k0 += 32) {
        gl_lds16(A + (size_t)ra0 * EMB + k0 + skb, As + (w * 512));
        gl_lds16(A + (size_t)ra1 * EMB + k0 + skb, As + (2048 + w * 512));
        gl_lds16(W + (size_t)rb0 * EMB + k0 + skb, Bs + (w * 512));
        gl_lds16(W + (size_t)rb1 * EMB + k0 + skb, Bs + (2048 + w * 512));
        __syncthreads();

        bf16x8 af[4], bfr[4];
#pragma unroll
        for (int m = 0; m < 4; m++)
            af[m] = *(const bf16x8*)&As[(wr * 64 + m * 16 + (lane & 15)) * 32 + (lane >> 4) * 8];
#pragma unroll
        for (int n = 0; n < 4; n++)
            bfr[n] = *(const bf16x8*)&Bs[(wc * 64 + n * 16 + (lane & 15)) * 32 + (lane >> 4) * 8];
#pragma unroll
        for (int m = 0; m < 4; m++)
#pragma unroll
            for (int n = 0; n < 4; n++)
                acc[m][n] = __builtin_amdgcn_mfma_f32_16x16x32_bf16(af[m], bfr[n], acc[m][n], 0, 0, 0);
        __syncthreads();
    }

    const int mat = n0 / EMB;                // 0,1,2 = q,k,v ; 3 = rel region
    const int nr  = n0 % EMB;
    const float* bias = (mat == 0) ? b0 : (mat == 1) ? b1 : b2;
    ushort* dst = (mat == 0) ? q_o : (mat == 1) ? k_o : v_o;

#pragma unroll
    for (int m = 0; m < 4; m++) {
#pragma unroll
        for (int r = 0; r < 4; r++) {
            const int gm = m0 + wr * 64 + m * 16 + (lane >> 4) * 4 + r;
            if (gm >= M) continue;
            const int bb = gm / SEQ, ss = gm - bb * SEQ;
#pragma unroll
            for (int n = 0; n < 4; n++) {
                const int cl = wc * 64 + n * 16 + (lane & 15);
                if (MODE == 0) {
                    if (mat < 3) {
                        const int col = nr + cl;
                        const float v = acc[m][n][r] + bias[col];
                        dst[(((size_t)bb * NH + (col >> 6)) * SEQ + ss) * HD + (col & 63)] = f2bf(v);
                    } else {
                        const int col2 = (n0 - 2304) + cl;
                        if (col2 < 672) {
                            const int h2 = col2 / 56, j = col2 - h2 * 56;
                            const float v = acc[m][n][r] + rbias[col2];
                            r_o[((size_t)(bb * NH + h2) * SEQ + ss) * 56 + j] = f2bf(v);
                        }
                    }
                } else {
                    const int col = nr + cl;
                    f_o[(size_t)gm * EMB + col] = acc[m][n][r] + bias[col];
                }
            }
        }
    }
}

// ---------------------------------------------------------------------------
// MFMA fused attention (r12 one-hot factorization) — unchanged.
// ---------------------------------------------------------------------------
__global__ __launch_bounds__(NT) void attn_mfma(
    const ushort* __restrict__ xq, const ushort* __restrict__ xk, const ushort* __restrict__ xv,
    const ushort* __restrict__ rxy_g,
    const float* __restrict__ v_tab_x, const float* __restrict__ v_tab_y,
    const int* __restrict__ x_dist, const int* __restrict__ y_dist,
    ushort* __restrict__ ao)
{
    __shared__ __align__(16) ushort K_s[SK * HD];        // 26624 B
    __shared__ __align__(16) ushort EXYs_s[SK * 40];     // 16640 B  [k][c]
    __shared__ __align__(16) ushort EXYT_s[32 * EP];     // 14848 B  [c][k]
    __shared__ __align__(16) ushort VT_s[HD * VP];       // 29696 B
    __shared__ __align__(16) ushort P_s[NW * 16 * PP];   // 51968 B
    __shared__ __align__(16) ushort vt_s[HD * TP];       // 8448 B
    __shared__ __align__(16) ushort h_s[NW][16][HP];     // 15232 B -> 163456

    const int bh = blockIdx.x;
    const int b  = bh / NH;
    const int h  = bh % NH;
    const size_t base = (size_t)bh * SEQ * HD;
    const ushort* __restrict__ rxy_b = rxy_g + (size_t)bh * SEQ * 56;
    const int tid = threadIdx.x;
    const int w = tid >> 6, lane = tid & 63;
    const int g = lane >> 4, c15 = lane & 15;

    // ---- stage K (bf16, swizzled 16B chunks; pad rows zero) ----
    for (int idx = tid; idx < SK * 8; idx += NT) {
        const int r = idx >> 3, c = idx & 7;
        uint4 v = make_uint4(0, 0, 0, 0);
        if (r < SEQ) v = *(const uint4*)(xk + base + r * HD + c * 8);
        *(uint4*)&K_s[r * HD + ((c ^ (r & 7)) << 3)] = v;
    }
    // ---- zero EXYs / EXYT ----
    for (int idx = tid; idx < SK * 40 / 8; idx += NT)
        *(uint4*)&EXYs_s[idx * 8] = make_uint4(0, 0, 0, 0);
    for (int idx = tid; idx < 32 * EP / 8; idx += NT)
        *(uint4*)&EXYT_s[idx * 8] = make_uint4(0, 0, 0, 0);
    // ---- VT pad columns zero ----
    for (int idx = tid; idx < HD * (VP - SEQ); idx += NT) {
        const int d = idx / (VP - SEQ), k = SEQ + idx - d * (VP - SEQ);
        VT_s[d * VP + k] = 0;
    }
    // ---- P zero all ----
    for (int idx = tid; idx < NW * 16 * PP / 8; idx += NT)
        *(uint4*)&P_s[idx * 8] = make_uint4(0, 0, 0, 0);
    // ---- VT transpose write, 16 consecutive lanes -> 16 consecutive k ----
    for (int idx = tid; idx < 16 * 8 * 13; idx += NT) {
        const int kq = idx & 15, t = idx >> 4;
        const int db = t & 7, kh = t >> 3;
        const int k = kh * 16 + kq;
        if (k >= SEQ) continue;
        uint4 v = *(const uint4*)(xv + base + k * HD + db * 8);
        ushort* col = &VT_s[(db * 8) * VP + k];
        col[0 * VP] = (ushort)(v.x); col[1 * VP] = (ushort)(v.x >> 16);
        col[2 * VP] = (ushort)(v.y); col[3 * VP] = (ushort)(v.y >> 16);
        col[4 * VP] = (ushort)(v.z); col[5 * VP] = (ushort)(v.z >> 16);
        col[6 * VP] = (ushort)(v.w); col[7 * VP] = (ushort)(v.w >> 16);
    }
    // ---- vtabT[d][e] staging ----
    for (int idx = tid; idx < HD * 64; idx += NT) {
        const int d = idx >> 6, e = idx & 63;
        float v = 0.f;
        if (d < 32) { if (e < 28) v = v_tab_x[e * 32 + d]; }
        else        { if (e >= 28 && e < 56) v = v_tab_y[(e - 28) * 32 + (d - 32)]; }
        vt_s[d * TP + e] = f2bf(v);
    }
    __syncthreads();   // zero EXY visible before one-hot fill (cross-wave)
    // ---- one-hot fill (cx from x_dist row 1; CLS -> flag col 14 / 30) ----
    for (int k = tid; k < SEQ; k += NT) {
        const int cx = (k == 0) ? 14 : (x_dist[SEQ + k] - 14);
        const int cy = (k == 0) ? 14 : (y_dist[SEQ + k] - 14);
        const ushort one = 0x3f80;   // bf16 1.0
        EXYs_s[k * 40 + cx]        = one;
        EXYs_s[k * 40 + 16 + cy]   = one;
        EXYT_s[cx * EP + k]        = one;
        EXYT_s[(16 + cy) * EP + k] = one;
    }
    __syncthreads();

    // ---- main loop: wave w owns q-tiles {w, w+7} ----
    for (int qt = w; qt < 13; qt += NW) {
        const int qrow = qt * 16 + c15;
        const int qld  = (qrow < SEQ) ? qrow : (SEQ - 1);
        const bf16x8 qa0 = *(const bf16x8*)(xq + base + (size_t)qld * HD + g * 8);
        const bf16x8 qa1 = *(const bf16x8*)(xq + base + (size_t)qld * HD + 32 + g * 8);

        // build augmented Q frag (dims 64..95): Raug[q][c], c = g*8..g*8+7
        uint4 up;
        {
            const ushort* rrow = rxy_b + qld * 56;
            const int cxq = (qld > 0) ? (x_dist[SEQ + qld] - 14) : 0;
            const int cyq = (qld > 0) ? (y_dist[SEQ + qld] - 14) : 0;
            unsigned uu[4] = {0, 0, 0, 0};
#pragma unroll
            for (int j = 0; j < 8; j++) {
                const int c = g * 8 + j;
                ushort v;
                if (qld == 0)      v = (c == 15 || c == 31) ? (ushort)0 : rrow[(c < 16) ? 0 : 28];
                else if (c < 14)   v = rrow[c - cxq + 14];
                else if (c == 14)  v = rrow[0];
                else if (c == 15)  v = 0;
                else if (c < 30)   v = rrow[28 + (c - 16) - cyq + 14];
                else if (c == 30)  v = rrow[28];
                else               v = 0;
                uu[j >> 1] |= ((unsigned)v) << ((j & 1) * 16);
            }
            up.x = uu[0]; up.y = uu[1]; up.z = uu[2]; up.w = uu[3];
        }
        const bf16x8 qa2 = *(bf16x8*)&up;

        // zero this wave's histogram
        {
            uint4* hz = (uint4*)h_s[w];
            for (int i = lane; i < 16 * HP / 8; i += 64) hz[i] = make_uint4(0, 0, 0, 0);
        }

        const int q4 = qt * 16 + 4 * g;
        float sum[4] = {0.f, 0.f, 0.f, 0.f};

        // fused augmented QK^T -> exp -> P write
#pragma unroll
        for (int kt = 0; kt < 13; kt++) {
            const int kr = kt * 16 + c15;
            bf16x8 kf0 = *(const bf16x8*)&K_s[kr * HD + (((0 + g) ^ (kr & 7)) << 3)];
            bf16x8 kf1 = *(const bf16x8*)&K_s[kr * HD + (((4 + g) ^ (kr & 7)) << 3)];
            bf16x8 kf2 = *(const bf16x8*)&EXYs_s[kr * 40 + g * 8];
            f32x4 a = (f32x4)0.f;
            a = __builtin_amdgcn_mfma_f32_16x16x32_bf16(qa0, kf0, a, 0, 0, 0);
            a = __builtin_amdgcn_mfma_f32_16x16x32_bf16(qa1, kf1, a, 0, 0, 0);
            a = __builtin_amdgcn_mfma_f32_16x16x32_bf16(qa2, kf2, a, 0, 0, 0);
#pragma unroll
            for (int r = 0; r < 4; r++) {
                const float l = a[r] * 0.125f - 8.0f;
                const float p = (kr < SEQ) ? __expf(l) : 0.f;
                sum[r] += p;
                P_s[(w * 16 + 4 * g + r) * PP + kr] = f2bf(p);
            }
        }
        float inv[4];
#pragma unroll
        for (int r = 0; r < 4; r++) {
            sum[r] += __shfl_xor(sum[r], 1);
            sum[r] += __shfl_xor(sum[r], 2);
            sum[r] += __shfl_xor(sum[r], 4);
            sum[r] += __shfl_xor(sum[r], 8);
            inv[r] = 1.f / sum[r];
        }

        // PXY = P x EXY (cols 0..15 = x, 16..31 = y)
        f32x4 px0 = (f32x4)0.f, px1 = (f32x4)0.f;
#pragma unroll
        for (int ks = 0; ks < 7; ks++) {
            bf16x8 pf = *(const bf16x8*)&P_s[(w * 16 + c15) * PP + ks * 32 + g * 8];
            bf16x8 e0 = *(const bf16x8*)&EXYT_s[c15 * EP + ks * 32 + g * 8];
            bf16x8 e1 = *(const bf16x8*)&EXYT_s[(16 + c15) * EP + ks * 32 + g * 8];
            px0 = __builtin_amdgcn_mfma_f32_16x16x32_bf16(pf, e0, px0, 0, 0, 0);
            px1 = __builtin_amdgcn_mfma_f32_16x16x32_bf16(pf, e1, px1, 0, 0, 0);
        }

        // q==0 CLS sums (all mass -> bin 0 / 28)
        float sx = px0[0], sy = px1[0];
        if (qt == 0) {
            sx += __shfl_xor(sx, 1); sx += __shfl_xor(sx, 2);
            sx += __shfl_xor(sx, 4); sx += __shfl_xor(sx, 8);
            sy += __shfl_xor(sy, 1); sy += __shfl_xor(sy, 2);
            sy += __shfl_xor(sy, 4); sy += __shfl_xor(sy, 8);
        }

        // histogram via injective remap (plain stores)
#pragma unroll
        for (int r = 0; r < 4; r++) {
            const int q = q4 + r;
            if (q >= SEQ) continue;
            const int ql = 4 * g + r;
            if (q == 0) {
                if (c15 == 14) { h_s[w][ql][0] = f2bf(sx); h_s[w][ql][28] = f2bf(sy); }
            } else {
                const int cxq2 = x_dist[SEQ + q] - 14;
                const int cyq2 = y_dist[SEQ + q] - 14;
                if (c15 < 14) {
                    h_s[w][ql][c15 - cxq2 + 14]        = f2bf(px0[r]);
                    h_s[w][ql][28 + c15 - cyq2 + 14]   = f2bf(px1[r]);
                } else if (c15 == 14) {
                    h_s[w][ql][0]  = f2bf(px0[r]);
                    h_s[w][ql][28] = f2bf(px1[r]);
                }
            }
        }

        // PV: O[q][d] = sum_k P[q][k] * VT[d][k]
        f32x4 o[4];
#pragma unroll
        for (int dt = 0; dt < 4; dt++) o[dt] = (f32x4)0.f;
#pragma unroll
        for (int ks = 0; ks < 7; ks++) {
            bf16x8 pf = *(const bf16x8*)&P_s[(w * 16 + c15) * PP + ks * 32 + g * 8];
#pragma unroll
            for (int dt = 0; dt < 4; dt++) {
                bf16x8 vf = *(const bf16x8*)&VT_s[(dt * 16 + c15) * VP + ks * 32 + g * 8];
                o[dt] = __builtin_amdgcn_mfma_f32_16x16x32_bf16(pf, vf, o[dt], 0, 0, 0);
            }
        }

        // v_pos via MFMA: O += H[q][e] x vtabT[d][e]
#pragma unroll
        for (int ks2 = 0; ks2 < 2; ks2++) {
            bf16x8 hf = *(const bf16x8*)&h_s[w][c15][ks2 * 32 + g * 8];
#pragma unroll
            for (int dt = 0; dt < 4; dt++) {
                bf16x8 tf = *(const bf16x8*)&vt_s[(dt * 16 + c15) * TP + ks2 * 32 + g * 8];
                o[dt] = __builtin_amdgcn_mfma_f32_16x16x32_bf16(hf, tf, o[dt], 0, 0, 0);
            }
        }

        // store (normalize; exp offset cancels)
#pragma unroll
        for (int dt = 0; dt < 4; dt++) {
            const int d = dt * 16 + c15;
#pragma unroll
            for (int r = 0; r < 4; r++) {
                const int q = q4 + r;
                if (q < SEQ)
                    ao[((size_t)(b * SEQ + q)) * EMB + h * HD + d] = f2bf(o[dt][r] * inv[r]);
            }
        }
    }
}

extern "C" void kernel_launch(void* const* d_in, const int* in_sizes, int n_in,
                              void* d_out, int out_size, void* d_ws, size_t ws_size,
                              hipStream_t stream) {
    const float* x       = (const float*)d_in[0];
    const float* Wq      = (const float*)d_in[1];
    const float* bq      = (const float*)d_in[2];
    const float* Wk      = (const float*)d_in[3];
    const float* bk      = (const float*)d_in[4];
    const float* Wv      = (const float*)d_in[5];
    const float* bv      = (const float*)d_in[6];
    const float* Wo      = (const float*)d_in[7];
    const float* bo      = (const float*)d_in[8];
    const float* q_tab_x = (const float*)d_in[9];
    const float* q_tab_y = (const float*)d_in[10];
    const float* v_tab_x = (const float*)d_in[11];
    const float* v_tab_y = (const float*)d_in[12];
    const int*   x_dist  = (const int*)d_in[13];
    const int*   y_dist  = (const int*)d_in[14];
    float* out = (float*)d_out;

    const int M  = in_sizes[0] / EMB;   // 12608
    const int Bc = M / SEQ;             // 64

    // ws carve (bf16 = ushort)
    ushort* xb   = (ushort*)d_ws;                       // M*768
    ushort* wqkv = xb   + (size_t)M * EMB;              // 3072*768 (q|k|v|Wr)
    ushort* wob  = wqkv + (size_t)3072 * EMB;           // 768*768
    ushort* xqb  = wob  + (size_t)EMB * EMB;            // M*768
    ushort* xkb  = xqb  + (size_t)M * EMB;
    ushort* xvb  = xkb  + (size_t)M * EMB;
    ushort* aob  = xvb  + (size_t)M * EMB;
    ushort* r_o  = aob  + (size_t)M * EMB;              // 768*197*56
    float*  rbia = (float*)(r_o + (size_t)Bc * NH * SEQ * 56);

    const int n4x = M * EMB / 4;
    cvt_k<<<dim3((n4x + 255) / 256), dim3(256), 0, stream>>>(x, xb, n4x);
    cvt_w4<<<dim3(2304), dim3(256), 0, stream>>>(Wq, Wk, Wv, Wo, wqkv, wob);
    wr_prep<<<dim3(2304), dim3(256), 0, stream>>>(Wq, q_tab_x, q_tab_y, wqkv);
    rbias_k<<<dim3(3), dim3(256), 0, stream>>>(bq, q_tab_x, q_tab_y, rbia);

    mfma_gemm<0><<<dim3((M + 127) / 128, 24), dim3(256), 0, stream>>>(
        xb, wqkv, bq, bk, bv, rbia, xqb, xkb, xvb, r_o, nullptr, M);

    attn_mfma<<<dim3(Bc * NH), dim3(NT), 0, stream>>>(
        xqb, xkb, xvb, r_o, v_tab_x, v_tab_y, x_dist, y_dist, aob);

    mfma_gemm<1><<<dim3((M + 127) / 128, 6), dim3(256), 0, stream>>>(
        aob, wob, bo, bo, bo, nullptr, nullptr, nullptr, nullptr, nullptr, out, M);
}